// Round 4
// baseline (8998.584 us; speedup 1.0000x reference)
//
#include <hip/hip_runtime.h>
#include <math.h>

// Problem constants
#define B_ 32
#define T_ 512
#define N_ 512
#define D_ 4
#define H_ 2048
#define C_ 128

typedef __attribute__((ext_vector_type(8))) short short8_t;
typedef __attribute__((ext_vector_type(4))) float float4_t;

// ---------------- helpers ----------------
__device__ __forceinline__ unsigned f2bf(float x) {
    unsigned u = __float_as_uint(x);
    return (u + 0x7fffu + ((u >> 16) & 1u)) >> 16;
}

// ---------------- sc f32 -> bf16 (packed u32 pairs) ----------------
__global__ __launch_bounds__(256) void cvt_sc_kernel(
    const float* __restrict__ in, unsigned* __restrict__ out) {
    int i = blockIdx.x * 256 + threadIdx.x;  // 131072 total
    out[i] = f2bf(in[2 * i]) | (f2bf(in[2 * i + 1]) << 16);
}

// ---------------- generic f32 GEMM: C[M,N] = A[M,K] @ B[K,N] + bias[N] ----------------
__global__ __launch_bounds__(256) void gemm_f32(
    const float* __restrict__ A, const float* __restrict__ Bm,
    const float* __restrict__ bias, float* __restrict__ C,
    int M, int N, int K) {
    __shared__ float As[16][132];
    __shared__ float Bs[16][132];
    const int tid = threadIdx.x;
    const int tx = tid & 15, ty = tid >> 4;
    const int bx = blockIdx.x, by = blockIdx.y;
    float acc[8][8];
#pragma unroll
    for (int i = 0; i < 8; ++i)
#pragma unroll
        for (int j = 0; j < 8; ++j) acc[i][j] = 0.f;
    const size_t Abase = (size_t)(by * 128) * K;
    for (int k0 = 0; k0 < K; k0 += 16) {
#pragma unroll
        for (int it = 0; it < 8; ++it) {
            int flat = it * 256 + tid;
            int r = flat >> 4, c = flat & 15;
            As[c][r] = A[Abase + (size_t)r * K + (k0 + c)];
        }
#pragma unroll
        for (int it = 0; it < 8; ++it) {
            int flat = it * 256 + tid;
            int r = flat >> 7, c = flat & 127;
            Bs[r][c] = Bm[(size_t)(k0 + r) * N + bx * 128 + c];
        }
        __syncthreads();
#pragma unroll
        for (int kk = 0; kk < 16; ++kk) {
            float a[8], bv[8];
            *(float4*)&a[0] = *(const float4*)&As[kk][ty * 8];
            *(float4*)&a[4] = *(const float4*)&As[kk][ty * 8 + 4];
            *(float4*)&bv[0] = *(const float4*)&Bs[kk][tx * 8];
            *(float4*)&bv[4] = *(const float4*)&Bs[kk][tx * 8 + 4];
#pragma unroll
            for (int i = 0; i < 8; ++i)
#pragma unroll
                for (int j = 0; j < 8; ++j)
                    acc[i][j] = fmaf(a[i], bv[j], acc[i][j]);
        }
        __syncthreads();
    }
#pragma unroll
    for (int i = 0; i < 8; ++i) {
        size_t row = (size_t)(by * 128 + ty * 8 + i);
#pragma unroll
        for (int j = 0; j < 8; ++j) {
            int col = bx * 128 + tx * 8 + j;
            C[row * (size_t)N + col] = acc[i][j] + bias[col];
        }
    }
}

// ---------------- mask GEMM: mh = sigmoid(G_shift @ Wm + bm); feat *= mh ----------------
// G rows remapped: output row (b,t) reads G[b, max(0, t-2)] (g written by scan into gamma).
// Epilogue scales feat[row, col*4 .. col*4+3] in place; writes no C.
__global__ __launch_bounds__(256) void gemm_mask(
    const float* __restrict__ G, const float* __restrict__ Wm,
    const float* __restrict__ bm, float* __restrict__ feat) {
    __shared__ float As[16][132];
    __shared__ float Bs[16][132];
    const int tid = threadIdx.x;
    const int tx = tid & 15, ty = tid >> 4;
    const int bx = blockIdx.x, by = blockIdx.y;
    float acc[8][8];
#pragma unroll
    for (int i = 0; i < 8; ++i)
#pragma unroll
        for (int j = 0; j < 8; ++j) acc[i][j] = 0.f;
    for (int k0 = 0; k0 < 512; k0 += 16) {
#pragma unroll
        for (int it = 0; it < 8; ++it) {
            int flat = it * 256 + tid;
            int r = flat >> 4, c = flat & 15;
            int row = by * 128 + r;
            int tt = row & 511;
            int src = (row & ~511) | (tt < 2 ? 0 : tt - 2);
            As[c][r] = G[(size_t)src * 512 + (k0 + c)];
        }
#pragma unroll
        for (int it = 0; it < 8; ++it) {
            int flat = it * 256 + tid;
            int r = flat >> 7, c = flat & 127;
            Bs[r][c] = Wm[(size_t)(k0 + r) * 512 + bx * 128 + c];
        }
        __syncthreads();
#pragma unroll
        for (int kk = 0; kk < 16; ++kk) {
            float a[8], bv[8];
            *(float4*)&a[0] = *(const float4*)&As[kk][ty * 8];
            *(float4*)&a[4] = *(const float4*)&As[kk][ty * 8 + 4];
            *(float4*)&bv[0] = *(const float4*)&Bs[kk][tx * 8];
            *(float4*)&bv[4] = *(const float4*)&Bs[kk][tx * 8 + 4];
#pragma unroll
            for (int i = 0; i < 8; ++i)
#pragma unroll
                for (int j = 0; j < 8; ++j)
                    acc[i][j] = fmaf(a[i], bv[j], acc[i][j]);
        }
        __syncthreads();
    }
#pragma unroll
    for (int i = 0; i < 8; ++i) {
        size_t row = (size_t)(by * 128 + ty * 8 + i);
#pragma unroll
        for (int j = 0; j < 8; ++j) {
            int col = bx * 128 + tx * 8 + j;
            float s = 1.f / (1.f + expf(-(acc[i][j] + bm[col])));
            float4* fp = (float4*)(feat + row * 2048 + col * 4);
            float4 v = *fp;
            v.x *= s; v.y *= s; v.z *= s; v.w *= s;
            *fp = v;
        }
    }
}

// ---------------- LayerNorm + LeakyReLU over rows of H=2048, in place ----------------
__device__ __forceinline__ float block_sum256(float v, float* red) {
#pragma unroll
    for (int o = 32; o > 0; o >>= 1) v += __shfl_down(v, o, 64);
    int w = threadIdx.x >> 6;
    if ((threadIdx.x & 63) == 0) red[w] = v;
    __syncthreads();
    float r = red[0] + red[1] + red[2] + red[3];
    __syncthreads();
    return r;
}

__global__ __launch_bounds__(256) void ln_leaky_kernel(
    float* __restrict__ Z, const float* __restrict__ gam, const float* __restrict__ bet) {
    __shared__ float red[4];
    const size_t row = blockIdx.x;
    float* zr = Z + row * H_;
    const int tid = threadIdx.x;
    float v[8];
    float s = 0.f;
#pragma unroll
    for (int i = 0; i < 8; ++i) { v[i] = zr[tid + i * 256]; s += v[i]; }
    s = block_sum256(s, red);
    float mu = s * (1.f / H_);
    float q = 0.f;
#pragma unroll
    for (int i = 0; i < 8; ++i) { float d = v[i] - mu; q += d * d; }
    q = block_sum256(q, red);
    float rs = rsqrtf(q * (1.f / H_) + 1e-5f);
#pragma unroll
    for (int i = 0; i < 8; ++i) {
        int c = tid + i * 256;
        float y = (v[i] - mu) * rs * gam[c] + bet[c];
        zr[c] = y > 0.f ? y : 0.1f * y;
    }
}

// ---------------- theta-scan: 16 blocks x 512 threads, NO cross-block sync ----------------
// Block owns 2 whole batches (all i, all d): every dependency is block-local.
// sc(bf16, 512x512=512KB) split: 8 M-tiles in VGPRs (areg, 64/lane), 8 in LDS,
// 16 streamed from L2 each step. Coupling = mfma_f32_16x16x32_bf16, B = [st|ct] 16 cols.
// g (theta_{t-2} mean-d) written into consumed gamma rows for the deferred mask GEMM.
#define SCAN_LDS_BYTES 149760
// LDS: lds_sc [8][16][520] u16 = 133120 B ; XT [16][520] u16 = 16640 B

__global__ __launch_bounds__(512, 1) void scan_kernel(
    const unsigned short* __restrict__ scb,  // [512][512] bf16
    float* __restrict__ gamma,               // [32][512][512] in: gamma, out(rows<510): g
    const float* __restrict__ omega,         // [512][4]
    float* __restrict__ feat) {              // [32][512][512][4] raw (pre-mask)
    extern __shared__ char smem[];
    unsigned short* lds_sc = (unsigned short*)smem;
    unsigned short* XT = (unsigned short*)(smem + 133120);

    const int tid = threadIdx.x;
    const int w = tid >> 6, l = tid & 63;
    const int c = l & 15, q = l >> 4;
    const int h = c >> 3, bd = c & 7, bl = (c >> 2) & 1, d = c & 3;
    const int bglob = (int)blockIdx.x * 2 + bl;
    const int o0 = q * 4 + 2 * h;  // row-in-tile base owned by this lane (+0,+1)

    // stage LDS sc tiles 8..15 (global rows 128..255)
    {
        const unsigned* g32 = (const unsigned*)scb;
        unsigned* l32 = (unsigned*)lds_sc;
        for (int it = 0; it < 64; ++it) {
            int idx = it * 512 + tid;
            int tile = idx >> 12, rem = idx & 4095;
            int row = rem >> 8, col2 = rem & 255;
            l32[(tile * 16 + row) * 260 + col2] = g32[(128 + tile * 16 + row) * 256 + col2];
        }
    }
    // register tile: global rows [w*16, +16)
    short8_t areg[16];
    {
        const unsigned short* arow = scb + (size_t)(w * 16 + c) * 512 + q * 8;
#pragma unroll
        for (int kk = 0; kk < 16; ++kk)
            areg[kk] = *(const short8_t*)(arow + kk * 32);
    }
    const unsigned short* s0 = scb + (size_t)(256 + w * 16 + c) * 512 + q * 8;
    const unsigned short* s1 = scb + (size_t)(384 + w * 16 + c) * 512 + q * 8;
    const unsigned short* al_base = lds_sc + (w * 16 + c) * 520 + q * 8;
    const unsigned short* bt_base = XT + c * 520 + q * 8;

    float om[4][2], th[4][2], sn[4][2], cs[4][2], g1[4][2], g2v[4][2];
#pragma unroll
    for (int mi = 0; mi < 4; ++mi)
#pragma unroll
        for (int rr = 0; rr < 2; ++rr) {
            int i = (mi * 8 + w) * 16 + o0 + rr;
            om[mi][rr] = omega[i * 4 + d];
            th[mi][rr] = 0.f; sn[mi][rr] = 0.f; cs[mi][rr] = 1.f;
            g1[mi][rr] = 0.f; g2v[mi][rr] = 0.f;
        }
    __syncthreads();

    for (int t = 0; t < T_; ++t) {
        // gamma loads (row t consumed before g overwrites it, same-lane ordering)
        float gv[4][2];
        {
            const float* grow = gamma + ((size_t)bglob * 512 + t) * 512;
#pragma unroll
            for (int mi = 0; mi < 4; ++mi)
#pragma unroll
                for (int rr = 0; rr < 2; ++rr)
                    gv[mi][rr] = grow[(mi * 8 + w) * 16 + o0 + rr];
        }

        float4_t acc0 = {0.f, 0.f, 0.f, 0.f}, acc1 = {0.f, 0.f, 0.f, 0.f};
        float4_t acc2 = {0.f, 0.f, 0.f, 0.f}, acc3 = {0.f, 0.f, 0.f, 0.f};
        if (t > 0) {
#pragma unroll
            for (int kk = 0; kk < 16; ++kk) {
                short8_t bf = *(const short8_t*)(bt_base + kk * 32);
                short8_t a1 = *(const short8_t*)(al_base + kk * 32);
                short8_t a2 = *(const short8_t*)(s0 + kk * 32);
                short8_t a3 = *(const short8_t*)(s1 + kk * 32);
                acc0 = __builtin_amdgcn_mfma_f32_16x16x32_bf16(areg[kk], bf, acc0, 0, 0, 0);
                acc1 = __builtin_amdgcn_mfma_f32_16x16x32_bf16(a1, bf, acc1, 0, 0, 0);
                acc2 = __builtin_amdgcn_mfma_f32_16x16x32_bf16(a2, bf, acc2, 0, 0, 0);
                acc3 = __builtin_amdgcn_mfma_f32_16x16x32_bf16(a3, bf, acc3, 0, 0, 0);
            }
        }
        __syncthreads();  // all XT reads of step t complete

        // combine st/ct halves, theta update, sincos, g
        float gcur[4][2];
#pragma unroll
        for (int mi = 0; mi < 4; ++mi) {
            float4_t acc = mi == 0 ? acc0 : mi == 1 ? acc1 : mi == 2 ? acc2 : acc3;
#pragma unroll
            for (int rr = 0; rr < 2; ++rr) {
                float own = h ? acc[2 + rr] : acc[rr];
                float send = h ? acc[rr] : acc[2 + rr];
                float recv = __shfl_xor(send, 8, 64);
                float Sst = h ? recv : own;
                float Sct = h ? own : recv;
                float coup = cs[mi][rr] * Sst - sn[mi][rr] * Sct;
                th[mi][rr] += 0.1f * (om[mi][rr] + gv[mi][rr] + (1.f / 512.f) * coup);
                sincosf(th[mi][rr], &sn[mi][rr], &cs[mi][rr]);
                float m = th[mi][rr];
                m += __shfl_xor(m, 1, 64);
                m += __shfl_xor(m, 2, 64);
                gcur[mi][rr] = 0.5f + 0.5f * sinf(m * 0.25f);
            }
        }
        if (t == 0) {
#pragma unroll
            for (int mi = 0; mi < 4; ++mi)
#pragma unroll
                for (int rr = 0; rr < 2; ++rr) {
                    g1[mi][rr] = gcur[mi][rr];
                    g2v[mi][rr] = gcur[mi][rr];
                }
        }
        // write new st/ct into XT (bf16 pairs)
#pragma unroll
        for (int mi = 0; mi < 4; ++mi) {
            int i0 = (mi * 8 + w) * 16 + o0;
            unsigned sp = f2bf(sn[mi][0]) | (f2bf(sn[mi][1]) << 16);
            unsigned cp = f2bf(cs[mi][0]) | (f2bf(cs[mi][1]) << 16);
            ((unsigned*)XT)[(bd * 520 + i0) >> 1] = sp;
            ((unsigned*)XT)[((8 + bd) * 520 + i0) >> 1] = cp;
        }
        // feat_raw(t) = sin(theta_t) * g(t)   (mask applied later)
        {
            float* frow = feat + ((size_t)bglob * 512 + t) * 2048;
#pragma unroll
            for (int mi = 0; mi < 4; ++mi)
#pragma unroll
                for (int rr = 0; rr < 2; ++rr) {
                    int i = (mi * 8 + w) * 16 + o0 + rr;
                    __builtin_nontemporal_store(sn[mi][rr] * g2v[mi][rr], frow + i * 4 + d);
                }
        }
        // publish g(t+2)=f(theta_t) into gamma row t (for deferred mask GEMM)
        if (d == 0 && t < 510) {
            float* gw = gamma + ((size_t)bglob * 512 + t) * 512;
#pragma unroll
            for (int mi = 0; mi < 4; ++mi)
#pragma unroll
                for (int rr = 0; rr < 2; ++rr)
                    gw[(mi * 8 + w) * 16 + o0 + rr] = gcur[mi][rr];
        }
        // rotate delay ring
#pragma unroll
        for (int mi = 0; mi < 4; ++mi)
#pragma unroll
            for (int rr = 0; rr < 2; ++rr) {
                g2v[mi][rr] = g1[mi][rr];
                g1[mi][rr] = gcur[mi][rr];
            }
        __syncthreads();  // XT writes visible for step t+1
    }
}

// ---------------- LIF membrane scan: cur -> spike, in place on [B,T,H] ----------------
__global__ __launch_bounds__(256) void mem_scan_kernel(float* __restrict__ io) {
    int tid = blockIdx.x * 256 + threadIdx.x;  // 65536 = B*H
    int h = tid & (H_ - 1), b = tid >> 11;
    float mem = 0.f;
    float* base = io + (size_t)b * T_ * H_ + h;
    for (int t = 0; t < T_; ++t) {
        float cur = base[(size_t)t * H_];
        mem = 0.5f * mem + cur;
        float sp = 1.f / (1.f + expf(-4.f * (mem - 1.f)));
        mem -= sp;
        base[(size_t)t * H_] = sp;
    }
}

// ---------------- conv1d(k=5,pad=2) over T + log_softmax over C ----------------
__global__ __launch_bounds__(128) void conv_lsm_kernel(
    const float* __restrict__ snn, const float* __restrict__ Wc,
    const float* __restrict__ bc, float* __restrict__ out0) {
    __shared__ float sl[36 * 128];
    const int b = blockIdx.x >> 4;
    const int tt0 = (blockIdx.x & 15) * 32;
    const int co = threadIdx.x;
    for (int r = 0; r < 36; ++r) {
        int t = tt0 + r - 2;
        sl[r * 128 + co] = (t >= 0 && t < T_) ? snn[(size_t)(b * T_ + t) * 128 + co] : 0.f;
    }
    __syncthreads();
    float acc[32];
#pragma unroll
    for (int i = 0; i < 32; ++i) acc[i] = 0.f;
    for (int ci = 0; ci < 128; ++ci) {
        const float* wp = &Wc[(size_t)(co * 128 + ci) * 5];
        float w0 = wp[0], w1 = wp[1], w2 = wp[2], w3 = wp[3], w4 = wp[4];
        const float* col = &sl[ci];
        float r0 = col[0 * 128], r1 = col[1 * 128], r2 = col[2 * 128], r3 = col[3 * 128];
#pragma unroll
        for (int i = 0; i < 32; ++i) {
            float r4 = col[(i + 4) * 128];
            acc[i] += w0 * r0 + w1 * r1 + w2 * r2 + w3 * r3 + w4 * r4;
            r0 = r1; r1 = r2; r2 = r3; r3 = r4;
        }
    }
    float bco = bc[co];
    __syncthreads();
    float* cl = sl;
#pragma unroll
    for (int i = 0; i < 32; ++i) cl[i * 129 + co] = acc[i] + bco;
    __syncthreads();
    if (co < 32) {
        int t = tt0 + co;
        float mx = -3.4e38f;
        for (int c = 0; c < 128; ++c) mx = fmaxf(mx, cl[co * 129 + c]);
        float se = 0.f;
        for (int c = 0; c < 128; ++c) se += expf(cl[co * 129 + c] - mx);
        float lse = mx + logf(se);
        for (int c = 0; c < 128; ++c)
            out0[((size_t)(b * 128 + c)) * T_ + t] = cl[co * 129 + c] - lse;
    }
}

// ---------------- launch ----------------
extern "C" void kernel_launch(void* const* d_in, const int* in_sizes, int n_in,
                              void* d_out, int out_size, void* d_ws, size_t ws_size,
                              hipStream_t stream) {
    (void)in_sizes; (void)n_in; (void)out_size; (void)ws_size;
    const float* x      = (const float*)d_in[0];
    const float* sc     = (const float*)d_in[1];
    const float* W_proj = (const float*)d_in[2];
    const float* b_proj = (const float*)d_in[3];
    const float* ln_g   = (const float*)d_in[4];
    const float* ln_b   = (const float*)d_in[5];
    const float* W_enc  = (const float*)d_in[6];
    const float* b_enc  = (const float*)d_in[7];
    const float* omega  = (const float*)d_in[8];
    const float* W_mask = (const float*)d_in[9];
    const float* b_mask = (const float*)d_in[10];
    const float* W_in   = (const float*)d_in[11];
    const float* b_in   = (const float*)d_in[12];
    const float* W_out  = (const float*)d_in[13];
    const float* b_out  = (const float*)d_in[14];
    const float* W_conv = (const float*)d_in[15];
    const float* b_conv = (const float*)d_in[16];

    float* out0 = (float*)d_out;                   // [B,C,T]
    float* out1 = out0 + (size_t)B_ * C_ * T_;     // [B,T,H] spikes (also Z/cur scratch)

    const int M = B_ * T_;  // 16384
    char* w = (char*)d_ws;
    float* gamma    = (float*)w;                               // [M, N] (gamma, then g)
    float* feat     = gamma + (size_t)M * N_;                  // [M, N*D]
    unsigned short* scb = (unsigned short*)(feat + (size_t)M * N_ * D_);  // [512][512] bf16
    float* snn_pre  = gamma;                                   // reuse after gemm_mask

    // sc f32 -> bf16
    cvt_sc_kernel<<<512, 256, 0, stream>>>(sc, (unsigned*)scb);
    // G1: Z = x @ W_proj + b_proj -> out1
    gemm_f32<<<dim3(H_ / 128, M / 128), 256, 0, stream>>>(x, W_proj, b_proj, out1, M, H_, N_);
    // LN + LeakyReLU in place
    ln_leaky_kernel<<<M, 256, 0, stream>>>(out1, ln_g, ln_b);
    // G2: gamma = Z @ W_enc + b_enc
    gemm_f32<<<dim3(N_ / 128, M / 128), 256, 0, stream>>>(out1, W_enc, b_enc, gamma, M, N_, H_);
    // theta scan -> feat(raw), g into gamma rows
    scan_kernel<<<16, 512, SCAN_LDS_BYTES, stream>>>(scb, gamma, omega, feat);
    // deferred mask: feat *= sigmoid(g_shift @ W_mask + b_mask)
    gemm_mask<<<dim3(N_ / 128, M / 128), 256, 0, stream>>>(gamma, W_mask, b_mask, feat);
    // G3: cur = feat @ W_in + b_in -> out1
    gemm_f32<<<dim3(H_ / 128, M / 128), 256, 0, stream>>>(feat, W_in, b_in, out1, M, H_, N_ * D_);
    // LIF membrane scan in place (final output 1)
    mem_scan_kernel<<<256, 256, 0, stream>>>(out1);
    // G4: snn_pre = spikes @ W_out + b_out
    gemm_f32<<<dim3(C_ / 128, M / 128), 256, 0, stream>>>(out1, W_out, b_out, snn_pre, M, C_, H_);
    // conv1d + log_softmax -> out0
    conv_lsm_kernel<<<dim3(B_ * 16), 128, 0, stream>>>(snn_pre, W_conv, b_conv, out0);
}

// Round 5
// 6618.460 us; speedup vs baseline: 1.3596x; 1.3596x over previous
//
#include <hip/hip_runtime.h>
#include <math.h>

// Problem constants
#define B_ 32
#define T_ 512
#define N_ 512
#define D_ 4
#define H_ 2048
#define C_ 128

typedef __attribute__((ext_vector_type(8))) short short8_t;
typedef __attribute__((ext_vector_type(4))) float float4_t;

// ---------------- helpers ----------------
__device__ __forceinline__ unsigned f2bf(float x) {
    unsigned u = __float_as_uint(x);
    return (u + 0x7fffu + ((u >> 16) & 1u)) >> 16;
}
// hardware sin/cos: input radians -> revolutions, fract-reduce, v_sin/v_cos
#define INV2PI 0.15915494309189535f
__device__ __forceinline__ float sin_hw(float x) {
    float r = x * INV2PI;
    r -= floorf(r);
    return __builtin_amdgcn_sinf(r);
}
__device__ __forceinline__ float cos_hw(float x) {
    float r = x * INV2PI;
    r -= floorf(r);
    return __builtin_amdgcn_cosf(r);
}

// ---------------- sc f32 -> bf16 (packed u32 pairs) ----------------
__global__ __launch_bounds__(256) void cvt_sc_kernel(
    const float* __restrict__ in, unsigned* __restrict__ out) {
    int i = blockIdx.x * 256 + threadIdx.x;  // 131072 total
    out[i] = f2bf(in[2 * i]) | (f2bf(in[2 * i + 1]) << 16);
}

// ---------------- generic f32 GEMM: C[M,N] = A[M,K] @ B[K,N] + bias[N] ----------------
__global__ __launch_bounds__(256) void gemm_f32(
    const float* __restrict__ A, const float* __restrict__ Bm,
    const float* __restrict__ bias, float* __restrict__ C,
    int M, int N, int K) {
    __shared__ float As[16][132];
    __shared__ float Bs[16][132];
    const int tid = threadIdx.x;
    const int tx = tid & 15, ty = tid >> 4;
    const int bx = blockIdx.x, by = blockIdx.y;
    float acc[8][8];
#pragma unroll
    for (int i = 0; i < 8; ++i)
#pragma unroll
        for (int j = 0; j < 8; ++j) acc[i][j] = 0.f;
    const size_t Abase = (size_t)(by * 128) * K;
    for (int k0 = 0; k0 < K; k0 += 16) {
#pragma unroll
        for (int it = 0; it < 8; ++it) {
            int flat = it * 256 + tid;
            int r = flat >> 4, c = flat & 15;
            As[c][r] = A[Abase + (size_t)r * K + (k0 + c)];
        }
#pragma unroll
        for (int it = 0; it < 8; ++it) {
            int flat = it * 256 + tid;
            int r = flat >> 7, c = flat & 127;
            Bs[r][c] = Bm[(size_t)(k0 + r) * N + bx * 128 + c];
        }
        __syncthreads();
#pragma unroll
        for (int kk = 0; kk < 16; ++kk) {
            float a[8], bv[8];
            *(float4*)&a[0] = *(const float4*)&As[kk][ty * 8];
            *(float4*)&a[4] = *(const float4*)&As[kk][ty * 8 + 4];
            *(float4*)&bv[0] = *(const float4*)&Bs[kk][tx * 8];
            *(float4*)&bv[4] = *(const float4*)&Bs[kk][tx * 8 + 4];
#pragma unroll
            for (int i = 0; i < 8; ++i)
#pragma unroll
                for (int j = 0; j < 8; ++j)
                    acc[i][j] = fmaf(a[i], bv[j], acc[i][j]);
        }
        __syncthreads();
    }
#pragma unroll
    for (int i = 0; i < 8; ++i) {
        size_t row = (size_t)(by * 128 + ty * 8 + i);
#pragma unroll
        for (int j = 0; j < 8; ++j) {
            int col = bx * 128 + tx * 8 + j;
            C[row * (size_t)N + col] = acc[i][j] + bias[col];
        }
    }
}

// ---------------- mask GEMM: mh = sigmoid(G_shift @ Wm + bm); feat *= mh ----------------
__global__ __launch_bounds__(256) void gemm_mask(
    const float* __restrict__ G, const float* __restrict__ Wm,
    const float* __restrict__ bm, float* __restrict__ feat) {
    __shared__ float As[16][132];
    __shared__ float Bs[16][132];
    const int tid = threadIdx.x;
    const int tx = tid & 15, ty = tid >> 4;
    const int bx = blockIdx.x, by = blockIdx.y;
    float acc[8][8];
#pragma unroll
    for (int i = 0; i < 8; ++i)
#pragma unroll
        for (int j = 0; j < 8; ++j) acc[i][j] = 0.f;
    for (int k0 = 0; k0 < 512; k0 += 16) {
#pragma unroll
        for (int it = 0; it < 8; ++it) {
            int flat = it * 256 + tid;
            int r = flat >> 4, c = flat & 15;
            int row = by * 128 + r;
            int tt = row & 511;
            int src = (row & ~511) | (tt < 2 ? 0 : tt - 2);
            As[c][r] = G[(size_t)src * 512 + (k0 + c)];
        }
#pragma unroll
        for (int it = 0; it < 8; ++it) {
            int flat = it * 256 + tid;
            int r = flat >> 7, c = flat & 127;
            Bs[r][c] = Wm[(size_t)(k0 + r) * 512 + bx * 128 + c];
        }
        __syncthreads();
#pragma unroll
        for (int kk = 0; kk < 16; ++kk) {
            float a[8], bv[8];
            *(float4*)&a[0] = *(const float4*)&As[kk][ty * 8];
            *(float4*)&a[4] = *(const float4*)&As[kk][ty * 8 + 4];
            *(float4*)&bv[0] = *(const float4*)&Bs[kk][tx * 8];
            *(float4*)&bv[4] = *(const float4*)&Bs[kk][tx * 8 + 4];
#pragma unroll
            for (int i = 0; i < 8; ++i)
#pragma unroll
                for (int j = 0; j < 8; ++j)
                    acc[i][j] = fmaf(a[i], bv[j], acc[i][j]);
        }
        __syncthreads();
    }
#pragma unroll
    for (int i = 0; i < 8; ++i) {
        size_t row = (size_t)(by * 128 + ty * 8 + i);
#pragma unroll
        for (int j = 0; j < 8; ++j) {
            int col = bx * 128 + tx * 8 + j;
            float s = 1.f / (1.f + __expf(-(acc[i][j] + bm[col])));
            float4* fp = (float4*)(feat + row * 2048 + col * 4);
            float4 v = *fp;
            v.x *= s; v.y *= s; v.z *= s; v.w *= s;
            *fp = v;
        }
    }
}

// ---------------- LayerNorm + LeakyReLU over rows of H=2048, in place ----------------
__device__ __forceinline__ float block_sum256(float v, float* red) {
#pragma unroll
    for (int o = 32; o > 0; o >>= 1) v += __shfl_down(v, o, 64);
    int w = threadIdx.x >> 6;
    if ((threadIdx.x & 63) == 0) red[w] = v;
    __syncthreads();
    float r = red[0] + red[1] + red[2] + red[3];
    __syncthreads();
    return r;
}

__global__ __launch_bounds__(256) void ln_leaky_kernel(
    float* __restrict__ Z, const float* __restrict__ gam, const float* __restrict__ bet) {
    __shared__ float red[4];
    const size_t row = blockIdx.x;
    float* zr = Z + row * H_;
    const int tid = threadIdx.x;
    float v[8];
    float s = 0.f;
#pragma unroll
    for (int i = 0; i < 8; ++i) { v[i] = zr[tid + i * 256]; s += v[i]; }
    s = block_sum256(s, red);
    float mu = s * (1.f / H_);
    float q = 0.f;
#pragma unroll
    for (int i = 0; i < 8; ++i) { float d = v[i] - mu; q += d * d; }
    q = block_sum256(q, red);
    float rs = rsqrtf(q * (1.f / H_) + 1e-5f);
#pragma unroll
    for (int i = 0; i < 8; ++i) {
        int c = tid + i * 256;
        float y = (v[i] - mu) * rs * gam[c] + bet[c];
        zr[c] = y > 0.f ? y : 0.1f * y;
    }
}

// ---------------- theta-scan: 16 blocks x 1024 threads, block-local ----------------
// Block owns 2 whole batches. 16 waves/CU (4/SIMD) for latency hiding.
// sc(bf16) split: 16 reg-tiles (one per wave, 64 VGPR), 8 LDS tiles (rows 256-383),
// 8 streamed from L2 (rows 384-511, waves 8-15). Coupling = mfma 16x16x32 bf16,
// B = [st|ct] 16 cols. Per-lane: 4 theta (2 tiles x 2 rows). HW trig.
#define SCAN_LDS_BYTES 149760
// LDS: lds_sc [8][16][520] u16 = 133120 B ; XT [16][520] u16 = 16640 B

__global__ __launch_bounds__(1024, 1) void scan_kernel(
    const unsigned short* __restrict__ scb,  // [512][512] bf16
    float* __restrict__ gamma,               // [32][512][512] in: gamma, out(rows<510): g
    const float* __restrict__ omega,         // [512][4]
    float* __restrict__ feat) {              // [32][512][512][4] raw (pre-mask)
    extern __shared__ char smem[];
    unsigned short* lds_sc = (unsigned short*)smem;
    unsigned short* XT = (unsigned short*)(smem + 133120);

    const int tid = threadIdx.x;
    const int w = tid >> 6, l = tid & 63;
    const int c = l & 15, q = l >> 4;
    const int h = c >> 3, bd = c & 7, bl = (c >> 2) & 1, d = c & 3;
    const int bglob = (int)blockIdx.x * 2 + bl;
    const int o0 = q * 4 + 2 * h;  // even row offset within tile; lane owns o0, o0+1

    // ---- stage LDS sc tiles (global rows 256..383) ----
    {
        const unsigned* g32 = (const unsigned*)scb;
        unsigned* l32 = (unsigned*)lds_sc;
        for (int it = 0; it < 32; ++it) {
            int idx = it * 1024 + tid;
            int row = idx >> 8, col = idx & 255;
            l32[row * 260 + col] = g32[(256 + row) * 256 + col];
        }
    }
    // ---- register tile: global rows [w*16, +16) ----
    short8_t areg[16];
    {
        const unsigned short* arow = scb + (size_t)(w * 16 + c) * 512 + q * 8;
#pragma unroll
        for (int kk = 0; kk < 16; ++kk)
            areg[kk] = *(const short8_t*)(arow + kk * 32);
    }
    // second tile source: LDS for waves 0-7 (rows 256+w*16), stream for waves 8-15
    const unsigned short* al_base = lds_sc + (w * 16 + c) * 520 + q * 8;          // w<8
    const unsigned short* gs_base = scb + (size_t)(256 + w * 16 + c) * 512 + q * 8;  // w>=8
    const unsigned short* bt_base = XT + c * 520 + q * 8;
    const int ibase0 = w * 16;
    const int ibase1 = 256 + w * 16;

    float om[2][2], th[2][2], sn[2][2], cs[2][2], g1[2][2], g2v[2][2];
#pragma unroll
    for (int mi = 0; mi < 2; ++mi)
#pragma unroll
        for (int rr = 0; rr < 2; ++rr) {
            int i = (mi ? ibase1 : ibase0) + o0 + rr;
            om[mi][rr] = omega[i * 4 + d];
            th[mi][rr] = 0.f; sn[mi][rr] = 0.f; cs[mi][rr] = 1.f;
            g1[mi][rr] = 0.f; g2v[mi][rr] = 0.f;
        }
    __syncthreads();

    for (int t = 0; t < T_; ++t) {
        // gamma loads (completed before first barrier -> safe vs later g writes)
        float gv[2][2];
        {
            const float* grow = gamma + ((size_t)bglob * 512 + t) * 512;
#pragma unroll
            for (int rr = 0; rr < 2; ++rr) {
                gv[0][rr] = grow[ibase0 + o0 + rr];
                gv[1][rr] = grow[ibase1 + o0 + rr];
            }
        }

        float4_t acc0 = {0.f, 0.f, 0.f, 0.f}, acc1 = {0.f, 0.f, 0.f, 0.f};
        if (t > 0) {
            if (w < 8) {
#pragma unroll
                for (int kk = 0; kk < 16; ++kk) {
                    short8_t bf = *(const short8_t*)(bt_base + kk * 32);
                    short8_t a1 = *(const short8_t*)(al_base + kk * 32);
                    acc0 = __builtin_amdgcn_mfma_f32_16x16x32_bf16(areg[kk], bf, acc0, 0, 0, 0);
                    acc1 = __builtin_amdgcn_mfma_f32_16x16x32_bf16(a1, bf, acc1, 0, 0, 0);
                }
            } else {
#pragma unroll
                for (int kk = 0; kk < 16; ++kk) {
                    short8_t bf = *(const short8_t*)(bt_base + kk * 32);
                    short8_t a1 = *(const short8_t*)(gs_base + kk * 32);
                    acc0 = __builtin_amdgcn_mfma_f32_16x16x32_bf16(areg[kk], bf, acc0, 0, 0, 0);
                    acc1 = __builtin_amdgcn_mfma_f32_16x16x32_bf16(a1, bf, acc1, 0, 0, 0);
                }
            }
        }
        __syncthreads();  // all XT reads of step t complete

        // combine halves, theta update, hw sincos, g
        float gcur[2][2];
#pragma unroll
        for (int mi = 0; mi < 2; ++mi) {
            float4_t acc = mi ? acc1 : acc0;
#pragma unroll
            for (int rr = 0; rr < 2; ++rr) {
                float own = h ? acc[2 + rr] : acc[rr];
                float send = h ? acc[rr] : acc[2 + rr];
                float recv = __shfl_xor(send, 8, 64);
                float Sst = h ? recv : own;
                float Sct = h ? own : recv;
                float coup = cs[mi][rr] * Sst - sn[mi][rr] * Sct;
                th[mi][rr] += 0.1f * (om[mi][rr] + gv[mi][rr] + (1.f / 512.f) * coup);
                sn[mi][rr] = sin_hw(th[mi][rr]);
                cs[mi][rr] = cos_hw(th[mi][rr]);
                float m = th[mi][rr];
                m += __shfl_xor(m, 1, 64);
                m += __shfl_xor(m, 2, 64);
                gcur[mi][rr] = 0.5f + 0.5f * sin_hw(m * 0.25f);
            }
        }
        if (t == 0) {
#pragma unroll
            for (int mi = 0; mi < 2; ++mi)
#pragma unroll
                for (int rr = 0; rr < 2; ++rr) {
                    g1[mi][rr] = gcur[mi][rr];
                    g2v[mi][rr] = gcur[mi][rr];
                }
        }
        // write new st/ct into XT (bf16 pairs)
        {
            unsigned sp0 = f2bf(sn[0][0]) | (f2bf(sn[0][1]) << 16);
            unsigned cp0 = f2bf(cs[0][0]) | (f2bf(cs[0][1]) << 16);
            unsigned sp1 = f2bf(sn[1][0]) | (f2bf(sn[1][1]) << 16);
            unsigned cp1 = f2bf(cs[1][0]) | (f2bf(cs[1][1]) << 16);
            ((unsigned*)XT)[(bd * 520 + ibase0 + o0) >> 1] = sp0;
            ((unsigned*)XT)[((8 + bd) * 520 + ibase0 + o0) >> 1] = cp0;
            ((unsigned*)XT)[(bd * 520 + ibase1 + o0) >> 1] = sp1;
            ((unsigned*)XT)[((8 + bd) * 520 + ibase1 + o0) >> 1] = cp1;
        }
        // feat_raw(t) = sin(theta_t) * g_{t-2}
        {
            float* frow = feat + ((size_t)bglob * 512 + t) * 2048;
#pragma unroll
            for (int rr = 0; rr < 2; ++rr) {
                frow[(ibase0 + o0 + rr) * 4 + d] = sn[0][rr] * g2v[0][rr];
                frow[(ibase1 + o0 + rr) * 4 + d] = sn[1][rr] * g2v[1][rr];
            }
        }
        // publish g (for deferred mask GEMM) into gamma row t
        if (d == 0 && t < 510) {
            float* gw = gamma + ((size_t)bglob * 512 + t) * 512;
#pragma unroll
            for (int rr = 0; rr < 2; ++rr) {
                gw[ibase0 + o0 + rr] = gcur[0][rr];
                gw[ibase1 + o0 + rr] = gcur[1][rr];
            }
        }
        // rotate delay ring
#pragma unroll
        for (int mi = 0; mi < 2; ++mi)
#pragma unroll
            for (int rr = 0; rr < 2; ++rr) {
                g2v[mi][rr] = g1[mi][rr];
                g1[mi][rr] = gcur[mi][rr];
            }
        __syncthreads();  // XT writes visible for step t+1
    }
}

// ---------------- LIF membrane scan: cur -> spike, in place on [B,T,H] ----------------
__global__ __launch_bounds__(256) void mem_scan_kernel(float* __restrict__ io) {
    int tid = blockIdx.x * 256 + threadIdx.x;  // 65536 = B*H
    int h = tid & (H_ - 1), b = tid >> 11;
    float mem = 0.f;
    float* base = io + (size_t)b * T_ * H_ + h;
    for (int t = 0; t < T_; ++t) {
        float cur = base[(size_t)t * H_];
        mem = 0.5f * mem + cur;
        float sp = 1.f / (1.f + __expf(-4.f * (mem - 1.f)));
        mem -= sp;
        base[(size_t)t * H_] = sp;
    }
}

// ---------------- conv1d(k=5,pad=2) over T + log_softmax over C ----------------
__global__ __launch_bounds__(128) void conv_lsm_kernel(
    const float* __restrict__ snn, const float* __restrict__ Wc,
    const float* __restrict__ bc, float* __restrict__ out0) {
    __shared__ float sl[36 * 128];
    const int b = blockIdx.x >> 4;
    const int tt0 = (blockIdx.x & 15) * 32;
    const int co = threadIdx.x;
    for (int r = 0; r < 36; ++r) {
        int t = tt0 + r - 2;
        sl[r * 128 + co] = (t >= 0 && t < T_) ? snn[(size_t)(b * T_ + t) * 128 + co] : 0.f;
    }
    __syncthreads();
    float acc[32];
#pragma unroll
    for (int i = 0; i < 32; ++i) acc[i] = 0.f;
    for (int ci = 0; ci < 128; ++ci) {
        const float* wp = &Wc[(size_t)(co * 128 + ci) * 5];
        float w0 = wp[0], w1 = wp[1], w2 = wp[2], w3 = wp[3], w4 = wp[4];
        const float* col = &sl[ci];
        float r0 = col[0 * 128], r1 = col[1 * 128], r2 = col[2 * 128], r3 = col[3 * 128];
#pragma unroll
        for (int i = 0; i < 32; ++i) {
            float r4 = col[(i + 4) * 128];
            acc[i] += w0 * r0 + w1 * r1 + w2 * r2 + w3 * r3 + w4 * r4;
            r0 = r1; r1 = r2; r2 = r3; r3 = r4;
        }
    }
    float bco = bc[co];
    __syncthreads();
    float* cl = sl;
#pragma unroll
    for (int i = 0; i < 32; ++i) cl[i * 129 + co] = acc[i] + bco;
    __syncthreads();
    if (co < 32) {
        int t = tt0 + co;
        float mx = -3.4e38f;
        for (int c = 0; c < 128; ++c) mx = fmaxf(mx, cl[co * 129 + c]);
        float se = 0.f;
        for (int c = 0; c < 128; ++c) se += __expf(cl[co * 129 + c] - mx);
        float lse = mx + __logf(se);
        for (int c = 0; c < 128; ++c)
            out0[((size_t)(b * 128 + c)) * T_ + t] = cl[co * 129 + c] - lse;
    }
}

// ---------------- launch ----------------
extern "C" void kernel_launch(void* const* d_in, const int* in_sizes, int n_in,
                              void* d_out, int out_size, void* d_ws, size_t ws_size,
                              hipStream_t stream) {
    (void)in_sizes; (void)n_in; (void)out_size; (void)ws_size;
    const float* x      = (const float*)d_in[0];
    const float* sc     = (const float*)d_in[1];
    const float* W_proj = (const float*)d_in[2];
    const float* b_proj = (const float*)d_in[3];
    const float* ln_g   = (const float*)d_in[4];
    const float* ln_b   = (const float*)d_in[5];
    const float* W_enc  = (const float*)d_in[6];
    const float* b_enc  = (const float*)d_in[7];
    const float* omega  = (const float*)d_in[8];
    const float* W_mask = (const float*)d_in[9];
    const float* b_mask = (const float*)d_in[10];
    const float* W_in   = (const float*)d_in[11];
    const float* b_in   = (const float*)d_in[12];
    const float* W_out  = (const float*)d_in[13];
    const float* b_out  = (const float*)d_in[14];
    const float* W_conv = (const float*)d_in[15];
    const float* b_conv = (const float*)d_in[16];

    float* out0 = (float*)d_out;                   // [B,C,T]
    float* out1 = out0 + (size_t)B_ * C_ * T_;     // [B,T,H] spikes (also Z/cur scratch)

    const int M = B_ * T_;  // 16384
    char* w = (char*)d_ws;
    float* gamma    = (float*)w;                               // [M, N] (gamma, then g)
    float* feat     = gamma + (size_t)M * N_;                  // [M, N*D]
    unsigned short* scb = (unsigned short*)(feat + (size_t)M * N_ * D_);  // [512][512] bf16
    float* snn_pre  = gamma;                                   // reuse after gemm_mask

    // sc f32 -> bf16
    cvt_sc_kernel<<<512, 256, 0, stream>>>(sc, (unsigned*)scb);
    // G1: Z = x @ W_proj + b_proj -> out1
    gemm_f32<<<dim3(H_ / 128, M / 128), 256, 0, stream>>>(x, W_proj, b_proj, out1, M, H_, N_);
    // LN + LeakyReLU in place
    ln_leaky_kernel<<<M, 256, 0, stream>>>(out1, ln_g, ln_b);
    // G2: gamma = Z @ W_enc + b_enc
    gemm_f32<<<dim3(N_ / 128, M / 128), 256, 0, stream>>>(out1, W_enc, b_enc, gamma, M, N_, H_);
    // theta scan -> feat(raw), g into gamma rows
    scan_kernel<<<16, 1024, SCAN_LDS_BYTES, stream>>>(scb, gamma, omega, feat);
    // deferred mask: feat *= sigmoid(g_shift @ W_mask + b_mask)
    gemm_mask<<<dim3(N_ / 128, M / 128), 256, 0, stream>>>(gamma, W_mask, b_mask, feat);
    // G3: cur = feat @ W_in + b_in -> out1
    gemm_f32<<<dim3(H_ / 128, M / 128), 256, 0, stream>>>(feat, W_in, b_in, out1, M, H_, N_ * D_);
    // LIF membrane scan in place (final output 1)
    mem_scan_kernel<<<256, 256, 0, stream>>>(out1);
    // G4: snn_pre = spikes @ W_out + b_out
    gemm_f32<<<dim3(C_ / 128, M / 128), 256, 0, stream>>>(out1, W_out, b_out, snn_pre, M, C_, H_);
    // conv1d + log_softmax -> out0
    conv_lsm_kernel<<<dim3(B_ * 16), 128, 0, stream>>>(snn_pre, W_conv, b_conv, out0);
}

// Round 6
// 5577.335 us; speedup vs baseline: 1.6134x; 1.1867x over previous
//
#include <hip/hip_runtime.h>
#include <math.h>

// Problem constants
#define B_ 32
#define T_ 512
#define N_ 512
#define D_ 4
#define H_ 2048
#define C_ 128

typedef __attribute__((ext_vector_type(8))) short short8_t;
typedef __attribute__((ext_vector_type(4))) float float4_t;

// ---------------- helpers ----------------
__device__ __forceinline__ unsigned f2bf(float x) {
    unsigned u = __float_as_uint(x);
    return (u + 0x7fffu + ((u >> 16) & 1u)) >> 16;
}
__device__ __forceinline__ float bf2f(unsigned short u) {
    return __uint_as_float((unsigned)u << 16);
}
#define INV2PI 0.15915494309189535f
__device__ __forceinline__ float sin_hw(float x) {
    float r = x * INV2PI;
    r -= floorf(r);
    return __builtin_amdgcn_sinf(r);
}
__device__ __forceinline__ float cos_hw(float x) {
    float r = x * INV2PI;
    r -= floorf(r);
    return __builtin_amdgcn_cosf(r);
}

// ---------------- f32 -> bf16 straight convert (packed pairs) ----------------
__global__ __launch_bounds__(256) void cvt_bf16_kernel(
    const float* __restrict__ in, unsigned* __restrict__ out, int n2) {
    int i = blockIdx.x * 256 + threadIdx.x;
    if (i < n2) out[i] = f2bf(in[2 * i]) | (f2bf(in[2 * i + 1]) << 16);
}

// ---------------- f32 [R,C] -> bf16 [C,R] transpose-convert ----------------
__global__ __launch_bounds__(256) void cvt_T_kernel(
    const float* __restrict__ in, unsigned short* __restrict__ out, int R, int C) {
    __shared__ float tl[32][33];
    const int tr = blockIdx.y * 32, tc = blockIdx.x * 32;
    const int a = threadIdx.x >> 3, b4 = (threadIdx.x & 7) * 4;
    float4 v = *(const float4*)(in + (size_t)(tr + a) * C + tc + b4);
    tl[a][b4] = v.x; tl[a][b4 + 1] = v.y; tl[a][b4 + 2] = v.z; tl[a][b4 + 3] = v.w;
    __syncthreads();
    unsigned* o32 = (unsigned*)out;
    size_t base = ((size_t)(tc + a) * R + tr + b4) >> 1;
    o32[base]     = f2bf(tl[b4][a])     | (f2bf(tl[b4 + 1][a]) << 16);
    o32[base + 1] = f2bf(tl[b4 + 2][a]) | (f2bf(tl[b4 + 3][a]) << 16);
}

// ---------------- bf16 MFMA GEMM: C[M,N] = A[M,K] @ BT[N,K]^T + bias ----------------
// 128x128 tile, BK=64, 256 threads (4 waves, 2x2), 4x4 frags of 16x16x32.
// EPI: 0 = f32 out, 1 = bf16 out, 2 = mask (sigmoid, scale featb rows in place).
// AREMAP: A row (b,t) read from (b, max(0,t-2)).
template <int EPI, bool AREMAP>
__global__ __launch_bounds__(256) void gemm_bf16(
    const unsigned short* __restrict__ A, const unsigned short* __restrict__ BT,
    const float* __restrict__ bias, void* __restrict__ Cout,
    int M, int N, int K) {
    __shared__ unsigned short Al[128 * 72];
    __shared__ unsigned short Bl[128 * 72];
    const int tid = threadIdx.x;
    const int wid = tid >> 6, l = tid & 63;
    const int c = l & 15, q = l >> 4;
    const int wr = wid >> 1, wc = wid & 1;
    const int m0 = blockIdx.y * 128, n0 = blockIdx.x * 128;
    float4_t acc[4][4];
#pragma unroll
    for (int i = 0; i < 4; ++i)
#pragma unroll
        for (int j = 0; j < 4; ++j) acc[i][j] = (float4_t){0.f, 0.f, 0.f, 0.f};

    const int sr = tid >> 1, sh = tid & 1;
    size_t a_row = (size_t)(m0 + sr);
    if (AREMAP) {
        int tt = (m0 + sr) & 511;
        a_row = (size_t)(((m0 + sr) & ~511) | (tt < 2 ? 0 : tt - 2));
    }
    const unsigned short* ag = A + a_row * K + sh * 32;
    const unsigned short* bg = BT + (size_t)(n0 + sr) * K + sh * 32;
    unsigned short* aw = Al + sr * 72 + sh * 32;
    unsigned short* bw = Bl + sr * 72 + sh * 32;

    for (int k0 = 0; k0 < K; k0 += 64) {
        uint4 av0 = *(const uint4*)(ag);
        uint4 av1 = *(const uint4*)(ag + 8);
        uint4 av2 = *(const uint4*)(ag + 16);
        uint4 av3 = *(const uint4*)(ag + 24);
        uint4 bv0 = *(const uint4*)(bg);
        uint4 bv1 = *(const uint4*)(bg + 8);
        uint4 bv2 = *(const uint4*)(bg + 16);
        uint4 bv3 = *(const uint4*)(bg + 24);
        __syncthreads();  // prior frag reads complete
        *(uint4*)(aw) = av0; *(uint4*)(aw + 8) = av1;
        *(uint4*)(aw + 16) = av2; *(uint4*)(aw + 24) = av3;
        *(uint4*)(bw) = bv0; *(uint4*)(bw + 8) = bv1;
        *(uint4*)(bw + 16) = bv2; *(uint4*)(bw + 24) = bv3;
        __syncthreads();
#pragma unroll
        for (int kk = 0; kk < 2; ++kk) {
            short8_t af[4], bf[4];
#pragma unroll
            for (int mt = 0; mt < 4; ++mt)
                af[mt] = *(const short8_t*)(Al + (wr * 64 + mt * 16 + c) * 72 + kk * 32 + q * 8);
#pragma unroll
            for (int nt = 0; nt < 4; ++nt)
                bf[nt] = *(const short8_t*)(Bl + (wc * 64 + nt * 16 + c) * 72 + kk * 32 + q * 8);
#pragma unroll
            for (int mt = 0; mt < 4; ++mt)
#pragma unroll
                for (int nt = 0; nt < 4; ++nt)
                    acc[mt][nt] = __builtin_amdgcn_mfma_f32_16x16x32_bf16(
                        af[mt], bf[nt], acc[mt][nt], 0, 0, 0);
        }
        ag += 64; bg += 64;
    }

#pragma unroll
    for (int mt = 0; mt < 4; ++mt) {
        int row = m0 + wr * 64 + mt * 16 + q * 4;
#pragma unroll
        for (int nt = 0; nt < 4; ++nt) {
            int col = n0 + wc * 64 + nt * 16 + c;
            float bs = bias[col];
            if (EPI == 0) {
                float* Cf = (float*)Cout;
#pragma unroll
                for (int r = 0; r < 4; ++r)
                    Cf[(size_t)(row + r) * N + col] = acc[mt][nt][r] + bs;
            } else if (EPI == 1) {
                unsigned short* Cb = (unsigned short*)Cout;
#pragma unroll
                for (int r = 0; r < 4; ++r)
                    Cb[(size_t)(row + r) * N + col] = (unsigned short)f2bf(acc[mt][nt][r] + bs);
            } else {
                unsigned short* Fb = (unsigned short*)Cout;
#pragma unroll
                for (int r = 0; r < 4; ++r) {
                    float s = 1.f / (1.f + __expf(-(acc[mt][nt][r] + bs)));
                    unsigned short* fp = Fb + (size_t)(row + r) * 2048 + col * 4;
                    unsigned u0 = *(const unsigned*)fp;
                    unsigned u1 = *(const unsigned*)(fp + 2);
                    float f0 = __uint_as_float(u0 << 16) * s;
                    float f1 = __uint_as_float(u0 & 0xffff0000u) * s;
                    float f2 = __uint_as_float(u1 << 16) * s;
                    float f3 = __uint_as_float(u1 & 0xffff0000u) * s;
                    *(unsigned*)fp = f2bf(f0) | (f2bf(f1) << 16);
                    *(unsigned*)(fp + 2) = f2bf(f2) | (f2bf(f3) << 16);
                }
            }
        }
    }
}

// ---------------- LayerNorm + LeakyReLU over bf16 rows of H=2048, in place ----------------
__device__ __forceinline__ float block_sum256(float v, float* red) {
#pragma unroll
    for (int o = 32; o > 0; o >>= 1) v += __shfl_down(v, o, 64);
    int w = threadIdx.x >> 6;
    if ((threadIdx.x & 63) == 0) red[w] = v;
    __syncthreads();
    float r = red[0] + red[1] + red[2] + red[3];
    __syncthreads();
    return r;
}

__global__ __launch_bounds__(256) void ln_leaky_kernel(
    unsigned short* __restrict__ Z, const float* __restrict__ gam,
    const float* __restrict__ bet) {
    __shared__ float red[4];
    unsigned short* zr = Z + (size_t)blockIdx.x * H_;
    const int tid = threadIdx.x;
    float v[8];
    float s = 0.f;
#pragma unroll
    for (int i = 0; i < 8; ++i) { v[i] = bf2f(zr[tid + i * 256]); s += v[i]; }
    s = block_sum256(s, red);
    float mu = s * (1.f / H_);
    float qq = 0.f;
#pragma unroll
    for (int i = 0; i < 8; ++i) { float dd = v[i] - mu; qq += dd * dd; }
    qq = block_sum256(qq, red);
    float rs = rsqrtf(qq * (1.f / H_) + 1e-5f);
#pragma unroll
    for (int i = 0; i < 8; ++i) {
        int cc = tid + i * 256;
        float y = (v[i] - mu) * rs * gam[cc] + bet[cc];
        zr[cc] = (unsigned short)f2bf(y > 0.f ? y : 0.1f * y);
    }
}

// ---------------- theta-scan v3: 16 blocks x 1024 threads, block-local ----------------
// XT double-buffered; ONE lgkm-only barrier per step (global stores float freely).
// sc: 16 reg tiles (rows 0-255) + 16 L2-streamed tiles (rows 256-511).
// feat, g emitted bf16. gamma(t+1) prefetched into registers.
#define SCAN_LDS_BYTES 33280
// LDS: XT0 [16][520] u16 @0 ; XT1 @16640

__global__ __launch_bounds__(1024, 1) void scan_kernel(
    const unsigned short* __restrict__ scb,  // [512][512] bf16
    const float* __restrict__ gamma,         // [32][512][512] f32
    const float* __restrict__ omega,         // [512][4]
    unsigned short* __restrict__ featb,      // [32][512][512][4] bf16 (pre-mask)
    unsigned short* __restrict__ gb) {       // [32][512][512] bf16
    extern __shared__ char smem[];
    unsigned short* XT0 = (unsigned short*)smem;
    unsigned short* XT1 = (unsigned short*)(smem + 16640);

    const int tid = threadIdx.x;
    const int w = tid >> 6, l = tid & 63;
    const int c = l & 15, q = l >> 4;
    const int h = c >> 3, bd = c & 7, bl = (c >> 2) & 1, d = c & 3;
    const int bglob = (int)blockIdx.x * 2 + bl;
    const int o0 = q * 4 + 2 * h;  // even row offset in tile; lane owns o0, o0+1

    // register tile: global rows [w*16, +16)
    short8_t areg[16];
    {
        const unsigned short* arow = scb + (size_t)(w * 16 + c) * 512 + q * 8;
#pragma unroll
        for (int kk = 0; kk < 16; ++kk)
            areg[kk] = *(const short8_t*)(arow + kk * 32);
    }
    const unsigned short* gs_base = scb + (size_t)(256 + w * 16 + c) * 512 + q * 8;
    const int ibase0 = w * 16;
    const int ibase1 = 256 + w * 16;

    float om[2][2], th[2][2], sn[2][2], cs[2][2], g1[2][2], g2v[2][2];
#pragma unroll
    for (int mi = 0; mi < 2; ++mi)
#pragma unroll
        for (int rr = 0; rr < 2; ++rr) {
            int i = (mi ? ibase1 : ibase0) + o0 + rr;
            om[mi][rr] = omega[i * 4 + d];
            th[mi][rr] = 0.f; sn[mi][rr] = 0.f; cs[mi][rr] = 1.f;
            g1[mi][rr] = 0.f; g2v[mi][rr] = 0.f;
        }

    // prefetch gamma(t=0)
    float gvn[2][2];
    {
        const float* grow = gamma + ((size_t)bglob * 512) * 512;
#pragma unroll
        for (int rr = 0; rr < 2; ++rr) {
            gvn[0][rr] = grow[ibase0 + o0 + rr];
            gvn[1][rr] = grow[ibase1 + o0 + rr];
        }
    }
    __syncthreads();

    for (int t = 0; t < T_; ++t) {
        const unsigned short* bt = ((t & 1) ? XT1 : XT0) + c * 520 + q * 8;
        unsigned short* xw = (t & 1) ? XT0 : XT1;

        float gv[2][2];
#pragma unroll
        for (int mi = 0; mi < 2; ++mi)
#pragma unroll
            for (int rr = 0; rr < 2; ++rr) gv[mi][rr] = gvn[mi][rr];
        if (t < T_ - 1) {
            const float* grow = gamma + ((size_t)bglob * 512 + t + 1) * 512;
#pragma unroll
            for (int rr = 0; rr < 2; ++rr) {
                gvn[0][rr] = grow[ibase0 + o0 + rr];
                gvn[1][rr] = grow[ibase1 + o0 + rr];
            }
        }

        float4_t acc0 = {0.f, 0.f, 0.f, 0.f}, acc1 = {0.f, 0.f, 0.f, 0.f};
        if (t > 0) {
#pragma unroll
            for (int kk = 0; kk < 16; ++kk) {
                short8_t bf = *(const short8_t*)(bt + kk * 32);
                short8_t a1 = *(const short8_t*)(gs_base + kk * 32);
                acc0 = __builtin_amdgcn_mfma_f32_16x16x32_bf16(areg[kk], bf, acc0, 0, 0, 0);
                acc1 = __builtin_amdgcn_mfma_f32_16x16x32_bf16(a1, bf, acc1, 0, 0, 0);
            }
        }

        // combine halves, theta update, hw sincos, g
        float gcur[2][2];
#pragma unroll
        for (int mi = 0; mi < 2; ++mi) {
            float4_t acc = mi ? acc1 : acc0;
#pragma unroll
            for (int rr = 0; rr < 2; ++rr) {
                float own = h ? acc[2 + rr] : acc[rr];
                float send = h ? acc[rr] : acc[2 + rr];
                float recv = __shfl_xor(send, 8, 64);
                float Sst = h ? recv : own;
                float Sct = h ? own : recv;
                float coup = cs[mi][rr] * Sst - sn[mi][rr] * Sct;
                th[mi][rr] += 0.1f * (om[mi][rr] + gv[mi][rr] + (1.f / 512.f) * coup);
                sn[mi][rr] = sin_hw(th[mi][rr]);
                cs[mi][rr] = cos_hw(th[mi][rr]);
                float m = th[mi][rr];
                m += __shfl_xor(m, 1, 64);
                m += __shfl_xor(m, 2, 64);
                gcur[mi][rr] = 0.5f + 0.5f * sin_hw(m * 0.25f);
            }
        }
        if (t == 0) {
#pragma unroll
            for (int mi = 0; mi < 2; ++mi)
#pragma unroll
                for (int rr = 0; rr < 2; ++rr) {
                    g1[mi][rr] = gcur[mi][rr];
                    g2v[mi][rr] = gcur[mi][rr];
                }
        }
        // write new st/ct into XT[next] (bf16 pairs)
        {
            unsigned sp0 = f2bf(sn[0][0]) | (f2bf(sn[0][1]) << 16);
            unsigned cp0 = f2bf(cs[0][0]) | (f2bf(cs[0][1]) << 16);
            unsigned sp1 = f2bf(sn[1][0]) | (f2bf(sn[1][1]) << 16);
            unsigned cp1 = f2bf(cs[1][0]) | (f2bf(cs[1][1]) << 16);
            ((unsigned*)xw)[(bd * 520 + ibase0 + o0) >> 1] = sp0;
            ((unsigned*)xw)[((8 + bd) * 520 + ibase0 + o0) >> 1] = cp0;
            ((unsigned*)xw)[(bd * 520 + ibase1 + o0) >> 1] = sp1;
            ((unsigned*)xw)[((8 + bd) * 520 + ibase1 + o0) >> 1] = cp1;
        }
        // feat_raw(t) = sin(theta_t) * g_{t-2}   (bf16, mask applied later)
        {
            unsigned short* frow = featb + ((size_t)bglob * 512 + t) * 2048;
#pragma unroll
            for (int rr = 0; rr < 2; ++rr) {
                frow[(ibase0 + o0 + rr) * 4 + d] = (unsigned short)f2bf(sn[0][rr] * g2v[0][rr]);
                frow[(ibase1 + o0 + rr) * 4 + d] = (unsigned short)f2bf(sn[1][rr] * g2v[1][rr]);
            }
        }
        // publish g(theta_t) bf16 (for deferred mask GEMM)
        if (d == 0) {
            unsigned* gw = (unsigned*)(gb + ((size_t)bglob * 512 + t) * 512);
            gw[(ibase0 + o0) >> 1] = f2bf(gcur[0][0]) | (f2bf(gcur[0][1]) << 16);
            gw[(ibase1 + o0) >> 1] = f2bf(gcur[1][0]) | (f2bf(gcur[1][1]) << 16);
        }
        // rotate delay ring
#pragma unroll
        for (int mi = 0; mi < 2; ++mi)
#pragma unroll
            for (int rr = 0; rr < 2; ++rr) {
                g2v[mi][rr] = g1[mi][rr];
                g1[mi][rr] = gcur[mi][rr];
            }
        // single per-step barrier: LDS (XT) ordered; global stores float freely
        asm volatile("s_waitcnt lgkmcnt(0)\n\ts_barrier" ::: "memory");
        __builtin_amdgcn_sched_barrier(0);
    }
}

// ---------------- LIF membrane scan: cur(f32) -> spike f32 (in place) + bf16 copy ----------------
__global__ __launch_bounds__(256) void mem_scan_kernel(
    float* __restrict__ io, unsigned short* __restrict__ spb) {
    int tid = blockIdx.x * 256 + threadIdx.x;  // 65536 = B*H
    int h = tid & (H_ - 1), b = tid >> 11;
    float mem = 0.f;
    float* base = io + (size_t)b * T_ * H_ + h;
    unsigned short* sb = spb + (size_t)b * T_ * H_ + h;
    for (int t = 0; t < T_; ++t) {
        float cur = base[(size_t)t * H_];
        mem = 0.5f * mem + cur;
        float sp = 1.f / (1.f + __expf(-4.f * (mem - 1.f)));
        mem -= sp;
        base[(size_t)t * H_] = sp;
        sb[(size_t)t * H_] = (unsigned short)f2bf(sp);
    }
}

// ---------------- conv1d(k=5,pad=2) over T + log_softmax over C ----------------
__global__ __launch_bounds__(128) void conv_lsm_kernel(
    const float* __restrict__ snn, const float* __restrict__ Wc,
    const float* __restrict__ bc, float* __restrict__ out0) {
    __shared__ float sl[36 * 128];
    const int b = blockIdx.x >> 4;
    const int tt0 = (blockIdx.x & 15) * 32;
    const int co = threadIdx.x;
    for (int r = 0; r < 36; ++r) {
        int t = tt0 + r - 2;
        sl[r * 128 + co] = (t >= 0 && t < T_) ? snn[(size_t)(b * T_ + t) * 128 + co] : 0.f;
    }
    __syncthreads();
    float acc[32];
#pragma unroll
    for (int i = 0; i < 32; ++i) acc[i] = 0.f;
    for (int ci = 0; ci < 128; ++ci) {
        const float* wp = &Wc[(size_t)(co * 128 + ci) * 5];
        float w0 = wp[0], w1 = wp[1], w2 = wp[2], w3 = wp[3], w4 = wp[4];
        const float* col = &sl[ci];
        float r0 = col[0 * 128], r1 = col[1 * 128], r2 = col[2 * 128], r3 = col[3 * 128];
#pragma unroll
        for (int i = 0; i < 32; ++i) {
            float r4 = col[(i + 4) * 128];
            acc[i] += w0 * r0 + w1 * r1 + w2 * r2 + w3 * r3 + w4 * r4;
            r0 = r1; r1 = r2; r2 = r3; r3 = r4;
        }
    }
    float bco = bc[co];
    __syncthreads();
    float* cl = sl;
#pragma unroll
    for (int i = 0; i < 32; ++i) cl[i * 129 + co] = acc[i] + bco;
    __syncthreads();
    if (co < 32) {
        int t = tt0 + co;
        float mx = -3.4e38f;
        for (int cc = 0; cc < 128; ++cc) mx = fmaxf(mx, cl[co * 129 + cc]);
        float se = 0.f;
        for (int cc = 0; cc < 128; ++cc) se += __expf(cl[co * 129 + cc] - mx);
        float lse = mx + __logf(se);
        for (int cc = 0; cc < 128; ++cc)
            out0[((size_t)(b * 128 + cc)) * T_ + t] = cl[co * 129 + cc] - lse;
    }
}

// ---------------- launch ----------------
extern "C" void kernel_launch(void* const* d_in, const int* in_sizes, int n_in,
                              void* d_out, int out_size, void* d_ws, size_t ws_size,
                              hipStream_t stream) {
    (void)in_sizes; (void)n_in; (void)out_size; (void)ws_size;
    const float* x      = (const float*)d_in[0];
    const float* sc     = (const float*)d_in[1];
    const float* W_proj = (const float*)d_in[2];
    const float* b_proj = (const float*)d_in[3];
    const float* ln_g   = (const float*)d_in[4];
    const float* ln_b   = (const float*)d_in[5];
    const float* W_enc  = (const float*)d_in[6];
    const float* b_enc  = (const float*)d_in[7];
    const float* omega  = (const float*)d_in[8];
    const float* W_mask = (const float*)d_in[9];
    const float* b_mask = (const float*)d_in[10];
    const float* W_in   = (const float*)d_in[11];
    const float* b_in   = (const float*)d_in[12];
    const float* W_out  = (const float*)d_in[13];
    const float* b_out  = (const float*)d_in[14];
    const float* W_conv = (const float*)d_in[15];
    const float* b_conv = (const float*)d_in[16];

    float* out0 = (float*)d_out;                   // [B,C,T]
    float* out1 = out0 + (size_t)B_ * C_ * T_;     // [B,T,H] f32: cur -> spikes

    const int M = B_ * T_;  // 16384
    char* w = (char*)d_ws;
    float*          gamma  = (float*)w;                                  // 33,554,432 B
    unsigned short* featb  = (unsigned short*)(w + 33554432);            // 67,108,864 B (Zb/featb/spb)
    unsigned short* gb     = (unsigned short*)(w + 100663296);           // 16,777,216 B (xb/gb)
    unsigned short* scb    = (unsigned short*)(w + 117440512);           // 524,288 B
    unsigned short* wprojT = (unsigned short*)(w + 117964800);           // [2048,512]  2 MB
    unsigned short* wencT  = (unsigned short*)(w + 120062976 - 1024);    // placeholder, fixed below
    wencT  = (unsigned short*)(w + 120061952);                           // [512,2048]  2 MB
    unsigned short* winT   = (unsigned short*)(w + 122159104);           // [2048,2048] 8 MB
    unsigned short* woutT  = (unsigned short*)(w + 130547712);           // [128,2048]  0.5 MB
    unsigned short* wmT    = (unsigned short*)(w + 131072000);           // [512,512]   0.5 MB
    unsigned short* xb  = gb;      // alias: xb dead before scan writes gb
    unsigned short* Zb  = featb;   // alias: Z dead before scan writes featb
    unsigned short* spb = featb;   // alias: featb dead after G3
    float* snn_pre = gamma;        // alias: gamma dead after scan

    // conversions
    cvt_bf16_kernel<<<512, 256, 0, stream>>>(sc, (unsigned*)scb, 131072);
    cvt_bf16_kernel<<<16384, 256, 0, stream>>>(x, (unsigned*)xb, 4194304);
    cvt_T_kernel<<<dim3(64, 16), 256, 0, stream>>>(W_proj, wprojT, 512, 2048);
    cvt_T_kernel<<<dim3(16, 64), 256, 0, stream>>>(W_enc, wencT, 2048, 512);
    cvt_T_kernel<<<dim3(64, 64), 256, 0, stream>>>(W_in, winT, 2048, 2048);
    cvt_T_kernel<<<dim3(4, 64), 256, 0, stream>>>(W_out, woutT, 2048, 128);
    cvt_T_kernel<<<dim3(16, 16), 256, 0, stream>>>(W_mask, wmT, 512, 512);

    // G1: Zb = bf16(x @ W_proj + b_proj)
    gemm_bf16<1, false><<<dim3(16, 128), 256, 0, stream>>>(xb, wprojT, b_proj, Zb, M, H_, N_);
    // LN + LeakyReLU in place (bf16)
    ln_leaky_kernel<<<M, 256, 0, stream>>>(Zb, ln_g, ln_b);
    // G2: gamma(f32) = Zb @ W_enc + b_enc
    gemm_bf16<0, false><<<dim3(4, 128), 256, 0, stream>>>(Zb, wencT, b_enc, gamma, M, N_, H_);
    // theta scan -> featb (bf16, pre-mask), gb (bf16)
    scan_kernel<<<16, 1024, SCAN_LDS_BYTES, stream>>>(scb, gamma, omega, featb, gb);
    // deferred mask: featb *= sigmoid(gb_shift @ W_mask + b_mask)
    gemm_bf16<2, true><<<dim3(4, 128), 256, 0, stream>>>(gb, wmT, b_mask, featb, M, N_, N_);
    // G3: cur(f32, out1) = featb @ W_in + b_in
    gemm_bf16<0, false><<<dim3(16, 128), 256, 0, stream>>>(featb, winT, b_in, out1, M, H_, N_ * D_);
    // LIF membrane scan in place + bf16 spikes
    mem_scan_kernel<<<256, 256, 0, stream>>>(out1, spb);
    // G4: snn_pre(f32) = spikes @ W_out + b_out
    gemm_bf16<0, false><<<dim3(1, 128), 256, 0, stream>>>(spb, woutT, b_out, snn_pre, M, C_, H_);
    // conv1d + log_softmax -> out0
    conv_lsm_kernel<<<dim3(B_ * 16), 128, 0, stream>>>(snn_pre, W_conv, b_conv, out0);
}

// Round 7
// 5554.356 us; speedup vs baseline: 1.6201x; 1.0041x over previous
//
#include <hip/hip_runtime.h>
#include <math.h>

// Problem constants
#define B_ 32
#define T_ 512
#define N_ 512
#define D_ 4
#define H_ 2048
#define C_ 128

typedef __attribute__((ext_vector_type(8))) short short8_t;
typedef __attribute__((ext_vector_type(4))) float float4_t;

// ---------------- helpers ----------------
__device__ __forceinline__ unsigned f2bf(float x) {
    unsigned u = __float_as_uint(x);
    return (u + 0x7fffu + ((u >> 16) & 1u)) >> 16;
}
__device__ __forceinline__ float bf2f(unsigned short u) {
    return __uint_as_float((unsigned)u << 16);
}
#define INV2PI 0.15915494309189535f
__device__ __forceinline__ float sin_hw(float x) {
    float r = x * INV2PI;
    r -= floorf(r);
    return __builtin_amdgcn_sinf(r);
}
__device__ __forceinline__ float cos_hw(float x) {
    float r = x * INV2PI;
    r -= floorf(r);
    return __builtin_amdgcn_cosf(r);
}

// ---------------- f32 -> bf16 straight convert (packed pairs) ----------------
__global__ __launch_bounds__(256) void cvt_bf16_kernel(
    const float* __restrict__ in, unsigned* __restrict__ out, int n2) {
    int i = blockIdx.x * 256 + threadIdx.x;
    if (i < n2) out[i] = f2bf(in[2 * i]) | (f2bf(in[2 * i + 1]) << 16);
}

// ---------------- f32 [R,C] -> bf16 [C,R] transpose-convert ----------------
__global__ __launch_bounds__(256) void cvt_T_kernel(
    const float* __restrict__ in, unsigned short* __restrict__ out, int R, int C) {
    __shared__ float tl[32][33];
    const int tr = blockIdx.y * 32, tc = blockIdx.x * 32;
    const int a = threadIdx.x >> 3, b4 = (threadIdx.x & 7) * 4;
    float4 v = *(const float4*)(in + (size_t)(tr + a) * C + tc + b4);
    tl[a][b4] = v.x; tl[a][b4 + 1] = v.y; tl[a][b4 + 2] = v.z; tl[a][b4 + 3] = v.w;
    __syncthreads();
    unsigned* o32 = (unsigned*)out;
    size_t base = ((size_t)(tc + a) * R + tr + b4) >> 1;
    o32[base]     = f2bf(tl[b4][a])     | (f2bf(tl[b4 + 1][a]) << 16);
    o32[base + 1] = f2bf(tl[b4 + 2][a]) | (f2bf(tl[b4 + 3][a]) << 16);
}

// ---------------- bf16 MFMA GEMM: C[M,N] = A[M,K] @ BT[N,K]^T + bias ----------------
// 128x128 tile, BK=64, 256 threads (4 waves, 2x2), 4x4 frags of 16x16x32.
// EPI: 0 = f32 out, 1 = bf16 out, 2 = mask (sigmoid, scale featb rows in place).
// AREMAP: A row (b,t) read from (b, max(0,t-2)).
template <int EPI, bool AREMAP>
__global__ __launch_bounds__(256) void gemm_bf16(
    const unsigned short* __restrict__ A, const unsigned short* __restrict__ BT,
    const float* __restrict__ bias, void* __restrict__ Cout,
    int M, int N, int K) {
    __shared__ unsigned short Al[128 * 72];
    __shared__ unsigned short Bl[128 * 72];
    const int tid = threadIdx.x;
    const int wid = tid >> 6, l = tid & 63;
    const int c = l & 15, q = l >> 4;
    const int wr = wid >> 1, wc = wid & 1;
    const int m0 = blockIdx.y * 128, n0 = blockIdx.x * 128;
    float4_t acc[4][4];
#pragma unroll
    for (int i = 0; i < 4; ++i)
#pragma unroll
        for (int j = 0; j < 4; ++j) acc[i][j] = (float4_t){0.f, 0.f, 0.f, 0.f};

    const int sr = tid >> 1, sh = tid & 1;
    size_t a_row = (size_t)(m0 + sr);
    if (AREMAP) {
        int tt = (m0 + sr) & 511;
        a_row = (size_t)(((m0 + sr) & ~511) | (tt < 2 ? 0 : tt - 2));
    }
    const unsigned short* ag = A + a_row * K + sh * 32;
    const unsigned short* bg = BT + (size_t)(n0 + sr) * K + sh * 32;
    unsigned short* aw = Al + sr * 72 + sh * 32;
    unsigned short* bw = Bl + sr * 72 + sh * 32;

    for (int k0 = 0; k0 < K; k0 += 64) {
        uint4 av0 = *(const uint4*)(ag);
        uint4 av1 = *(const uint4*)(ag + 8);
        uint4 av2 = *(const uint4*)(ag + 16);
        uint4 av3 = *(const uint4*)(ag + 24);
        uint4 bv0 = *(const uint4*)(bg);
        uint4 bv1 = *(const uint4*)(bg + 8);
        uint4 bv2 = *(const uint4*)(bg + 16);
        uint4 bv3 = *(const uint4*)(bg + 24);
        __syncthreads();  // prior frag reads complete
        *(uint4*)(aw) = av0; *(uint4*)(aw + 8) = av1;
        *(uint4*)(aw + 16) = av2; *(uint4*)(aw + 24) = av3;
        *(uint4*)(bw) = bv0; *(uint4*)(bw + 8) = bv1;
        *(uint4*)(bw + 16) = bv2; *(uint4*)(bw + 24) = bv3;
        __syncthreads();
#pragma unroll
        for (int kk = 0; kk < 2; ++kk) {
            short8_t af[4], bf[4];
#pragma unroll
            for (int mt = 0; mt < 4; ++mt)
                af[mt] = *(const short8_t*)(Al + (wr * 64 + mt * 16 + c) * 72 + kk * 32 + q * 8);
#pragma unroll
            for (int nt = 0; nt < 4; ++nt)
                bf[nt] = *(const short8_t*)(Bl + (wc * 64 + nt * 16 + c) * 72 + kk * 32 + q * 8);
#pragma unroll
            for (int mt = 0; mt < 4; ++mt)
#pragma unroll
                for (int nt = 0; nt < 4; ++nt)
                    acc[mt][nt] = __builtin_amdgcn_mfma_f32_16x16x32_bf16(
                        af[mt], bf[nt], acc[mt][nt], 0, 0, 0);
        }
        ag += 64; bg += 64;
    }

#pragma unroll
    for (int mt = 0; mt < 4; ++mt) {
        int row = m0 + wr * 64 + mt * 16 + q * 4;
#pragma unroll
        for (int nt = 0; nt < 4; ++nt) {
            int col = n0 + wc * 64 + nt * 16 + c;
            float bs = bias[col];
            if (EPI == 0) {
                float* Cf = (float*)Cout;
#pragma unroll
                for (int r = 0; r < 4; ++r)
                    Cf[(size_t)(row + r) * N + col] = acc[mt][nt][r] + bs;
            } else if (EPI == 1) {
                unsigned short* Cb = (unsigned short*)Cout;
#pragma unroll
                for (int r = 0; r < 4; ++r)
                    Cb[(size_t)(row + r) * N + col] = (unsigned short)f2bf(acc[mt][nt][r] + bs);
            } else {
                unsigned short* Fb = (unsigned short*)Cout;
#pragma unroll
                for (int r = 0; r < 4; ++r) {
                    float s = 1.f / (1.f + __expf(-(acc[mt][nt][r] + bs)));
                    unsigned short* fp = Fb + (size_t)(row + r) * 2048 + col * 4;
                    unsigned u0 = *(const unsigned*)fp;
                    unsigned u1 = *(const unsigned*)(fp + 2);
                    float f0 = __uint_as_float(u0 << 16) * s;
                    float f1 = __uint_as_float(u0 & 0xffff0000u) * s;
                    float f2 = __uint_as_float(u1 << 16) * s;
                    float f3 = __uint_as_float(u1 & 0xffff0000u) * s;
                    *(unsigned*)fp = f2bf(f0) | (f2bf(f1) << 16);
                    *(unsigned*)(fp + 2) = f2bf(f2) | (f2bf(f3) << 16);
                }
            }
        }
    }
}

// ---------------- LayerNorm + LeakyReLU over bf16 rows of H=2048, in place ----------------
__device__ __forceinline__ float block_sum256(float v, float* red) {
#pragma unroll
    for (int o = 32; o > 0; o >>= 1) v += __shfl_down(v, o, 64);
    int w = threadIdx.x >> 6;
    if ((threadIdx.x & 63) == 0) red[w] = v;
    __syncthreads();
    float r = red[0] + red[1] + red[2] + red[3];
    __syncthreads();
    return r;
}

__global__ __launch_bounds__(256) void ln_leaky_kernel(
    unsigned short* __restrict__ Z, const float* __restrict__ gam,
    const float* __restrict__ bet) {
    __shared__ float red[4];
    unsigned short* zr = Z + (size_t)blockIdx.x * H_;
    const int tid = threadIdx.x;
    float v[8];
    float s = 0.f;
#pragma unroll
    for (int i = 0; i < 8; ++i) { v[i] = bf2f(zr[tid + i * 256]); s += v[i]; }
    s = block_sum256(s, red);
    float mu = s * (1.f / H_);
    float qq = 0.f;
#pragma unroll
    for (int i = 0; i < 8; ++i) { float dd = v[i] - mu; qq += dd * dd; }
    qq = block_sum256(qq, red);
    float rs = rsqrtf(qq * (1.f / H_) + 1e-5f);
#pragma unroll
    for (int i = 0; i < 8; ++i) {
        int cc = tid + i * 256;
        float y = (v[i] - mu) * rs * gam[cc] + bet[cc];
        zr[cc] = (unsigned short)f2bf(y > 0.f ? y : 0.1f * y);
    }
}

// ---------------- theta-scan v4: 16 blocks x 1024 threads, block-local ----------------
// __launch_bounds__(1024,4): 128 VGPR cap so areg[16] (64 VGPR) is truly resident.
// sc split: 16 reg tiles (rows 0-255) + 7 LDS tiles (rows 256-367) + 9 streamed (368-511).
// XT double-buffered (init sin=0,cos=1 -> uniform t=0); ONE lgkm-only raw barrier/step.
#define SCAN_LDS_BYTES 149760
// LDS: XT0 [16][520]u16 @0 ; XT1 @16640 ; sc_lds [112][520]u16 @33280

__global__ __launch_bounds__(1024, 4) void scan_kernel(
    const unsigned short* __restrict__ scb,  // [512][512] bf16
    const float* __restrict__ gamma,         // [32][512][512] f32
    const float* __restrict__ omega,         // [512][4]
    unsigned short* __restrict__ featb,      // [32][512][512][4] bf16 (pre-mask)
    unsigned short* __restrict__ gb) {       // [32][512][512] bf16
    extern __shared__ char smem[];
    unsigned short* XT0 = (unsigned short*)smem;
    unsigned short* XT1 = (unsigned short*)(smem + 16640);
    unsigned short* sc_lds = (unsigned short*)(smem + 33280);

    const int tid = threadIdx.x;
    const int w = tid >> 6, l = tid & 63;
    const int c = l & 15, q = l >> 4;
    const int h = c >> 3, bd = c & 7, bl = (c >> 2) & 1, d = c & 3;
    const int bglob = (int)blockIdx.x * 2 + bl;
    const int o0 = q * 4 + 2 * h;  // even row offset in tile; lane owns o0, o0+1

    // ---- XT0 init: sin rows (0-7) = 0, cos rows (8-15) = 1.0bf16 ----
    for (int idx = tid; idx < 16 * 260; idx += 1024)
        ((unsigned*)XT0)[idx] = (idx < 8 * 260) ? 0u : 0x3f803f80u;
    // ---- stage LDS sc tiles: global rows 256..367 ----
    {
        const unsigned* g32 = (const unsigned*)scb;
        unsigned* l32 = (unsigned*)sc_lds;
        for (int it = 0; it < 28; ++it) {
            int idx = it * 1024 + tid;
            int row = idx >> 8, col = idx & 255;
            l32[row * 260 + col] = g32[(256 + row) * 256 + col];
        }
    }
    // ---- register tile: global rows [w*16, +16) ----
    short8_t areg[16];
    {
        const unsigned short* arow = scb + (size_t)(w * 16 + c) * 512 + q * 8;
#pragma unroll
        for (int kk = 0; kk < 16; ++kk)
            areg[kk] = *(const short8_t*)(arow + kk * 32);
    }
    // second tile source: LDS for waves 0-6, L2 stream for waves 7-15
    const unsigned short* al_base = sc_lds + (w * 16 + c) * 520 + q * 8;             // w<7
    const unsigned short* gs_base = scb + (size_t)(256 + w * 16 + c) * 512 + q * 8;  // w>=7
    const int ibase0 = w * 16;
    const int ibase1 = 256 + w * 16;

    float om[2][2], th[2][2], sn[2][2], cs[2][2], g1[2][2], g2v[2][2];
#pragma unroll
    for (int mi = 0; mi < 2; ++mi)
#pragma unroll
        for (int rr = 0; rr < 2; ++rr) {
            int i = (mi ? ibase1 : ibase0) + o0 + rr;
            om[mi][rr] = omega[i * 4 + d];
            th[mi][rr] = 0.f; sn[mi][rr] = 0.f; cs[mi][rr] = 1.f;
            g1[mi][rr] = 0.f; g2v[mi][rr] = 0.f;
        }

    // prefetch gamma(t=0)
    float gvn[2][2];
    {
        const float* grow = gamma + ((size_t)bglob * 512) * 512;
#pragma unroll
        for (int rr = 0; rr < 2; ++rr) {
            gvn[0][rr] = grow[ibase0 + o0 + rr];
            gvn[1][rr] = grow[ibase1 + o0 + rr];
        }
    }
    __syncthreads();

    for (int t = 0; t < T_; ++t) {
        const unsigned short* bt = ((t & 1) ? XT1 : XT0) + c * 520 + q * 8;
        unsigned short* xw = (t & 1) ? XT0 : XT1;

        float gv[2][2];
#pragma unroll
        for (int mi = 0; mi < 2; ++mi)
#pragma unroll
            for (int rr = 0; rr < 2; ++rr) gv[mi][rr] = gvn[mi][rr];
        if (t < T_ - 1) {
            const float* grow = gamma + ((size_t)bglob * 512 + t + 1) * 512;
#pragma unroll
            for (int rr = 0; rr < 2; ++rr) {
                gvn[0][rr] = grow[ibase0 + o0 + rr];
                gvn[1][rr] = grow[ibase1 + o0 + rr];
            }
        }

        float4_t acc0 = {0.f, 0.f, 0.f, 0.f}, acc1 = {0.f, 0.f, 0.f, 0.f};
        if (w < 7) {
#pragma unroll
            for (int kk = 0; kk < 16; ++kk) {
                short8_t bf = *(const short8_t*)(bt + kk * 32);
                short8_t a1 = *(const short8_t*)(al_base + kk * 32);
                acc0 = __builtin_amdgcn_mfma_f32_16x16x32_bf16(areg[kk], bf, acc0, 0, 0, 0);
                acc1 = __builtin_amdgcn_mfma_f32_16x16x32_bf16(a1, bf, acc1, 0, 0, 0);
            }
        } else {
#pragma unroll
            for (int kk = 0; kk < 16; ++kk) {
                short8_t bf = *(const short8_t*)(bt + kk * 32);
                short8_t a1 = *(const short8_t*)(gs_base + kk * 32);
                acc0 = __builtin_amdgcn_mfma_f32_16x16x32_bf16(areg[kk], bf, acc0, 0, 0, 0);
                acc1 = __builtin_amdgcn_mfma_f32_16x16x32_bf16(a1, bf, acc1, 0, 0, 0);
            }
        }

        // combine halves, theta update, hw sincos, g
        float gcur[2][2];
#pragma unroll
        for (int mi = 0; mi < 2; ++mi) {
            float4_t acc = mi ? acc1 : acc0;
#pragma unroll
            for (int rr = 0; rr < 2; ++rr) {
                float own = h ? acc[2 + rr] : acc[rr];
                float send = h ? acc[rr] : acc[2 + rr];
                float recv = __shfl_xor(send, 8, 64);
                float Sst = h ? recv : own;
                float Sct = h ? own : recv;
                float coup = cs[mi][rr] * Sst - sn[mi][rr] * Sct;
                th[mi][rr] += 0.1f * (om[mi][rr] + gv[mi][rr] + (1.f / 512.f) * coup);
                sn[mi][rr] = sin_hw(th[mi][rr]);
                cs[mi][rr] = cos_hw(th[mi][rr]);
                float m = th[mi][rr];
                m += __shfl_xor(m, 1, 64);
                m += __shfl_xor(m, 2, 64);
                gcur[mi][rr] = 0.5f + 0.5f * sin_hw(m * 0.25f);
            }
        }
        if (t == 0) {
#pragma unroll
            for (int mi = 0; mi < 2; ++mi)
#pragma unroll
                for (int rr = 0; rr < 2; ++rr) {
                    g1[mi][rr] = gcur[mi][rr];
                    g2v[mi][rr] = gcur[mi][rr];
                }
        }
        // write new st/ct into XT[next] (bf16 pairs)
        {
            unsigned sp0 = f2bf(sn[0][0]) | (f2bf(sn[0][1]) << 16);
            unsigned cp0 = f2bf(cs[0][0]) | (f2bf(cs[0][1]) << 16);
            unsigned sp1 = f2bf(sn[1][0]) | (f2bf(sn[1][1]) << 16);
            unsigned cp1 = f2bf(cs[1][0]) | (f2bf(cs[1][1]) << 16);
            ((unsigned*)xw)[(bd * 520 + ibase0 + o0) >> 1] = sp0;
            ((unsigned*)xw)[((8 + bd) * 520 + ibase0 + o0) >> 1] = cp0;
            ((unsigned*)xw)[(bd * 520 + ibase1 + o0) >> 1] = sp1;
            ((unsigned*)xw)[((8 + bd) * 520 + ibase1 + o0) >> 1] = cp1;
        }
        // feat_raw(t) = sin(theta_t) * g_{t-2}   (bf16, mask applied later)
        {
            unsigned short* frow = featb + ((size_t)bglob * 512 + t) * 2048;
#pragma unroll
            for (int rr = 0; rr < 2; ++rr) {
                frow[(ibase0 + o0 + rr) * 4 + d] = (unsigned short)f2bf(sn[0][rr] * g2v[0][rr]);
                frow[(ibase1 + o0 + rr) * 4 + d] = (unsigned short)f2bf(sn[1][rr] * g2v[1][rr]);
            }
        }
        // publish g(theta_t) bf16 (for deferred mask GEMM)
        if (d == 0) {
            unsigned* gw = (unsigned*)(gb + ((size_t)bglob * 512 + t) * 512);
            gw[(ibase0 + o0) >> 1] = f2bf(gcur[0][0]) | (f2bf(gcur[0][1]) << 16);
            gw[(ibase1 + o0) >> 1] = f2bf(gcur[1][0]) | (f2bf(gcur[1][1]) << 16);
        }
        // rotate delay ring
#pragma unroll
        for (int mi = 0; mi < 2; ++mi)
#pragma unroll
            for (int rr = 0; rr < 2; ++rr) {
                g2v[mi][rr] = g1[mi][rr];
                g1[mi][rr] = gcur[mi][rr];
            }
        // LDS-only wait + raw barrier (no vmcnt drain; global stores float freely)
        asm volatile("s_waitcnt lgkmcnt(0)" ::: "memory");
        __builtin_amdgcn_s_barrier();
    }
}

// ---------------- LIF membrane scan: cur(f32) -> spike f32 (in place) + bf16 copy ----------------
__global__ __launch_bounds__(256) void mem_scan_kernel(
    float* __restrict__ io, unsigned short* __restrict__ spb) {
    int tid = blockIdx.x * 256 + threadIdx.x;  // 65536 = B*H
    int h = tid & (H_ - 1), b = tid >> 11;
    float mem = 0.f;
    float* base = io + (size_t)b * T_ * H_ + h;
    unsigned short* sb = spb + (size_t)b * T_ * H_ + h;
    for (int t = 0; t < T_; ++t) {
        float cur = base[(size_t)t * H_];
        mem = 0.5f * mem + cur;
        float sp = 1.f / (1.f + __expf(-4.f * (mem - 1.f)));
        mem -= sp;
        base[(size_t)t * H_] = sp;
        sb[(size_t)t * H_] = (unsigned short)f2bf(sp);
    }
}

// ---------------- conv1d(k=5,pad=2) over T + log_softmax over C ----------------
__global__ __launch_bounds__(128) void conv_lsm_kernel(
    const float* __restrict__ snn, const float* __restrict__ Wc,
    const float* __restrict__ bc, float* __restrict__ out0) {
    __shared__ float sl[36 * 128];
    const int b = blockIdx.x >> 4;
    const int tt0 = (blockIdx.x & 15) * 32;
    const int co = threadIdx.x;
    for (int r = 0; r < 36; ++r) {
        int t = tt0 + r - 2;
        sl[r * 128 + co] = (t >= 0 && t < T_) ? snn[(size_t)(b * T_ + t) * 128 + co] : 0.f;
    }
    __syncthreads();
    float acc[32];
#pragma unroll
    for (int i = 0; i < 32; ++i) acc[i] = 0.f;
    for (int ci = 0; ci < 128; ++ci) {
        const float* wp = &Wc[(size_t)(co * 128 + ci) * 5];
        float w0 = wp[0], w1 = wp[1], w2 = wp[2], w3 = wp[3], w4 = wp[4];
        const float* col = &sl[ci];
        float r0 = col[0 * 128], r1 = col[1 * 128], r2 = col[2 * 128], r3 = col[3 * 128];
#pragma unroll
        for (int i = 0; i < 32; ++i) {
            float r4 = col[(i + 4) * 128];
            acc[i] += w0 * r0 + w1 * r1 + w2 * r2 + w3 * r3 + w4 * r4;
            r0 = r1; r1 = r2; r2 = r3; r3 = r4;
        }
    }
    float bco = bc[co];
    __syncthreads();
    float* cl = sl;
#pragma unroll
    for (int i = 0; i < 32; ++i) cl[i * 129 + co] = acc[i] + bco;
    __syncthreads();
    if (co < 32) {
        int t = tt0 + co;
        float mx = -3.4e38f;
        for (int cc = 0; cc < 128; ++cc) mx = fmaxf(mx, cl[co * 129 + cc]);
        float se = 0.f;
        for (int cc = 0; cc < 128; ++cc) se += __expf(cl[co * 129 + cc] - mx);
        float lse = mx + __logf(se);
        for (int cc = 0; cc < 128; ++cc)
            out0[((size_t)(b * 128 + cc)) * T_ + t] = cl[co * 129 + cc] - lse;
    }
}

// ---------------- launch ----------------
extern "C" void kernel_launch(void* const* d_in, const int* in_sizes, int n_in,
                              void* d_out, int out_size, void* d_ws, size_t ws_size,
                              hipStream_t stream) {
    (void)in_sizes; (void)n_in; (void)out_size; (void)ws_size;
    const float* x      = (const float*)d_in[0];
    const float* sc     = (const float*)d_in[1];
    const float* W_proj = (const float*)d_in[2];
    const float* b_proj = (const float*)d_in[3];
    const float* ln_g   = (const float*)d_in[4];
    const float* ln_b   = (const float*)d_in[5];
    const float* W_enc  = (const float*)d_in[6];
    const float* b_enc  = (const float*)d_in[7];
    const float* omega  = (const float*)d_in[8];
    const float* W_mask = (const float*)d_in[9];
    const float* b_mask = (const float*)d_in[10];
    const float* W_in   = (const float*)d_in[11];
    const float* b_in   = (const float*)d_in[12];
    const float* W_out  = (const float*)d_in[13];
    const float* b_out  = (const float*)d_in[14];
    const float* W_conv = (const float*)d_in[15];
    const float* b_conv = (const float*)d_in[16];

    float* out0 = (float*)d_out;                   // [B,C,T]
    float* out1 = out0 + (size_t)B_ * C_ * T_;     // [B,T,H] f32: cur -> spikes

    const int M = B_ * T_;  // 16384
    char* w = (char*)d_ws;
    float*          gamma  = (float*)w;                                  // 33,554,432 B
    unsigned short* featb  = (unsigned short*)(w + 33554432);            // 67,108,864 B (Zb/featb/spb)
    unsigned short* gb     = (unsigned short*)(w + 100663296);           // 16,777,216 B (xb/gb)
    unsigned short* scb    = (unsigned short*)(w + 117440512);           // 524,288 B
    unsigned short* wprojT = (unsigned short*)(w + 117964800);           // [2048,512]  2 MB
    unsigned short* wencT  = (unsigned short*)(w + 120061952);           // [512,2048]  2 MB
    unsigned short* winT   = (unsigned short*)(w + 122159104);           // [2048,2048] 8 MB
    unsigned short* woutT  = (unsigned short*)(w + 130547712);           // [128,2048]  0.5 MB
    unsigned short* wmT    = (unsigned short*)(w + 131072000);           // [512,512]   0.5 MB
    unsigned short* xb  = gb;      // alias: xb dead before scan writes gb
    unsigned short* Zb  = featb;   // alias: Z dead before scan writes featb
    unsigned short* spb = featb;   // alias: featb dead after G3
    float* snn_pre = gamma;        // alias: gamma dead after scan

    // conversions
    cvt_bf16_kernel<<<512, 256, 0, stream>>>(sc, (unsigned*)scb, 131072);
    cvt_bf16_kernel<<<16384, 256, 0, stream>>>(x, (unsigned*)xb, 4194304);
    cvt_T_kernel<<<dim3(64, 16), 256, 0, stream>>>(W_proj, wprojT, 512, 2048);
    cvt_T_kernel<<<dim3(16, 64), 256, 0, stream>>>(W_enc, wencT, 2048, 512);
    cvt_T_kernel<<<dim3(64, 64), 256, 0, stream>>>(W_in, winT, 2048, 2048);
    cvt_T_kernel<<<dim3(4, 64), 256, 0, stream>>>(W_out, woutT, 2048, 128);
    cvt_T_kernel<<<dim3(16, 16), 256, 0, stream>>>(W_mask, wmT, 512, 512);

    // G1: Zb = bf16(x @ W_proj + b_proj)
    gemm_bf16<1, false><<<dim3(16, 128), 256, 0, stream>>>(xb, wprojT, b_proj, Zb, M, H_, N_);
    // LN + LeakyReLU in place (bf16)
    ln_leaky_kernel<<<M, 256, 0, stream>>>(Zb, ln_g, ln_b);
    // G2: gamma(f32) = Zb @ W_enc + b_enc
    gemm_bf16<0, false><<<dim3(4, 128), 256, 0, stream>>>(Zb, wencT, b_enc, gamma, M, N_, H_);
    // theta scan -> featb (bf16, pre-mask), gb (bf16)
    scan_kernel<<<16, 1024, SCAN_LDS_BYTES, stream>>>(scb, gamma, omega, featb, gb);
    // deferred mask: featb *= sigmoid(gb_shift @ W_mask + b_mask)
    gemm_bf16<2, true><<<dim3(4, 128), 256, 0, stream>>>(gb, wmT, b_mask, featb, M, N_, N_);
    // G3: cur(f32, out1) = featb @ W_in + b_in
    gemm_bf16<0, false><<<dim3(16, 128), 256, 0, stream>>>(featb, winT, b_in, out1, M, H_, N_ * D_);
    // LIF membrane scan in place + bf16 spikes
    mem_scan_kernel<<<256, 256, 0, stream>>>(out1, spb);
    // G4: snn_pre(f32) = spikes @ W_out + b_out
    gemm_bf16<0, false><<<dim3(1, 128), 256, 0, stream>>>(spb, woutT, b_out, snn_pre, M, C_, H_);
    // conv1d + log_softmax -> out0
    conv_lsm_kernel<<<dim3(B_ * 16), 128, 0, stream>>>(snn_pre, W_conv, b_conv, out0);
}

// Round 8
// 4083.938 us; speedup vs baseline: 2.2034x; 1.3600x over previous
//
#include <hip/hip_runtime.h>
#include <math.h>

// Problem constants
#define B_ 32
#define T_ 512
#define N_ 512
#define D_ 4
#define H_ 2048
#define C_ 128

typedef __attribute__((ext_vector_type(8))) short short8_t;
typedef __attribute__((ext_vector_type(4))) float float4_t;

// ---------------- helpers ----------------
__device__ __forceinline__ unsigned f2bf(float x) {
    unsigned u = __float_as_uint(x);
    return (u + 0x7fffu + ((u >> 16) & 1u)) >> 16;
}
__device__ __forceinline__ float bf2f(unsigned u) {
    return __uint_as_float(u << 16);
}
#define INV2PI 0.15915494309189535f
__device__ __forceinline__ float sin_hw(float x) {
    float r = x * INV2PI;
    r -= floorf(r);
    return __builtin_amdgcn_sinf(r);
}
__device__ __forceinline__ float cos_hw(float x) {
    float r = x * INV2PI;
    r -= floorf(r);
    return __builtin_amdgcn_cosf(r);
}

// ---------------- f32 -> bf16 straight convert (packed pairs) ----------------
__global__ __launch_bounds__(256) void cvt_bf16_kernel(
    const float* __restrict__ in, unsigned* __restrict__ out, int n2) {
    int i = blockIdx.x * 256 + threadIdx.x;
    if (i < n2) out[i] = f2bf(in[2 * i]) | (f2bf(in[2 * i + 1]) << 16);
}

// ---------------- f32 [R,C] -> bf16 [C,R] transpose-convert ----------------
__global__ __launch_bounds__(256) void cvt_T_kernel(
    const float* __restrict__ in, unsigned short* __restrict__ out, int R, int C) {
    __shared__ float tl[32][33];
    const int tr = blockIdx.y * 32, tc = blockIdx.x * 32;
    const int a = threadIdx.x >> 3, b4 = (threadIdx.x & 7) * 4;
    float4 v = *(const float4*)(in + (size_t)(tr + a) * C + tc + b4);
    tl[a][b4] = v.x; tl[a][b4 + 1] = v.y; tl[a][b4 + 2] = v.z; tl[a][b4 + 3] = v.w;
    __syncthreads();
    unsigned* o32 = (unsigned*)out;
    size_t base = ((size_t)(tc + a) * R + tr + b4) >> 1;
    o32[base]     = f2bf(tl[b4][a])     | (f2bf(tl[b4 + 1][a]) << 16);
    o32[base + 1] = f2bf(tl[b4 + 2][a]) | (f2bf(tl[b4 + 3][a]) << 16);
}

// ---------------- bf16 MFMA GEMM: C[M,N] = A[M,K] @ BT[N,K]^T + bias ----------------
// 128x128 tile, BK=64, 256 threads (4 waves, 2x2), 4x4 frags of 16x16x32.
// EPI: 0 = f32 out, 1 = bf16 out, 2 = mask (sigmoid, scale featb rows in place).
// AREMAP: A row (b,t) read from (b, max(0,t-2)).
template <int EPI, bool AREMAP>
__global__ __launch_bounds__(256) void gemm_bf16(
    const unsigned short* __restrict__ A, const unsigned short* __restrict__ BT,
    const float* __restrict__ bias, void* __restrict__ Cout,
    int M, int N, int K) {
    __shared__ unsigned short Al[128 * 72];
    __shared__ unsigned short Bl[128 * 72];
    const int tid = threadIdx.x;
    const int wid = tid >> 6, l = tid & 63;
    const int c = l & 15, q = l >> 4;
    const int wr = wid >> 1, wc = wid & 1;
    const int m0 = blockIdx.y * 128, n0 = blockIdx.x * 128;
    float4_t acc[4][4];
#pragma unroll
    for (int i = 0; i < 4; ++i)
#pragma unroll
        for (int j = 0; j < 4; ++j) acc[i][j] = (float4_t){0.f, 0.f, 0.f, 0.f};

    const int sr = tid >> 1, sh = tid & 1;
    size_t a_row = (size_t)(m0 + sr);
    if (AREMAP) {
        int tt = (m0 + sr) & 511;
        a_row = (size_t)(((m0 + sr) & ~511) | (tt < 2 ? 0 : tt - 2));
    }
    const unsigned short* ag = A + a_row * K + sh * 32;
    const unsigned short* bg = BT + (size_t)(n0 + sr) * K + sh * 32;
    unsigned short* aw = Al + sr * 72 + sh * 32;
    unsigned short* bw = Bl + sr * 72 + sh * 32;

    for (int k0 = 0; k0 < K; k0 += 64) {
        uint4 av0 = *(const uint4*)(ag);
        uint4 av1 = *(const uint4*)(ag + 8);
        uint4 av2 = *(const uint4*)(ag + 16);
        uint4 av3 = *(const uint4*)(ag + 24);
        uint4 bv0 = *(const uint4*)(bg);
        uint4 bv1 = *(const uint4*)(bg + 8);
        uint4 bv2 = *(const uint4*)(bg + 16);
        uint4 bv3 = *(const uint4*)(bg + 24);
        __syncthreads();  // prior frag reads complete
        *(uint4*)(aw) = av0; *(uint4*)(aw + 8) = av1;
        *(uint4*)(aw + 16) = av2; *(uint4*)(aw + 24) = av3;
        *(uint4*)(bw) = bv0; *(uint4*)(bw + 8) = bv1;
        *(uint4*)(bw + 16) = bv2; *(uint4*)(bw + 24) = bv3;
        __syncthreads();
#pragma unroll
        for (int kk = 0; kk < 2; ++kk) {
            short8_t af[4], bf[4];
#pragma unroll
            for (int mt = 0; mt < 4; ++mt)
                af[mt] = *(const short8_t*)(Al + (wr * 64 + mt * 16 + c) * 72 + kk * 32 + q * 8);
#pragma unroll
            for (int nt = 0; nt < 4; ++nt)
                bf[nt] = *(const short8_t*)(Bl + (wc * 64 + nt * 16 + c) * 72 + kk * 32 + q * 8);
#pragma unroll
            for (int mt = 0; mt < 4; ++mt)
#pragma unroll
                for (int nt = 0; nt < 4; ++nt)
                    acc[mt][nt] = __builtin_amdgcn_mfma_f32_16x16x32_bf16(
                        af[mt], bf[nt], acc[mt][nt], 0, 0, 0);
        }
        ag += 64; bg += 64;
    }

#pragma unroll
    for (int mt = 0; mt < 4; ++mt) {
        int row = m0 + wr * 64 + mt * 16 + q * 4;
#pragma unroll
        for (int nt = 0; nt < 4; ++nt) {
            int col = n0 + wc * 64 + nt * 16 + c;
            float bs = bias[col];
            if (EPI == 0) {
                float* Cf = (float*)Cout;
#pragma unroll
                for (int r = 0; r < 4; ++r)
                    Cf[(size_t)(row + r) * N + col] = acc[mt][nt][r] + bs;
            } else if (EPI == 1) {
                unsigned short* Cb = (unsigned short*)Cout;
#pragma unroll
                for (int r = 0; r < 4; ++r)
                    Cb[(size_t)(row + r) * N + col] = (unsigned short)f2bf(acc[mt][nt][r] + bs);
            } else {
                unsigned short* Fb = (unsigned short*)Cout;
#pragma unroll
                for (int r = 0; r < 4; ++r) {
                    float s = 1.f / (1.f + __expf(-(acc[mt][nt][r] + bs)));
                    unsigned short* fp = Fb + (size_t)(row + r) * 2048 + col * 4;
                    unsigned u0 = *(const unsigned*)fp;
                    unsigned u1 = *(const unsigned*)(fp + 2);
                    float f0 = bf2f(u0 & 0xffffu) * s;
                    float f1 = __uint_as_float(u0 & 0xffff0000u) * s;
                    float f2 = bf2f(u1 & 0xffffu) * s;
                    float f3 = __uint_as_float(u1 & 0xffff0000u) * s;
                    *(unsigned*)fp = f2bf(f0) | (f2bf(f1) << 16);
                    *(unsigned*)(fp + 2) = f2bf(f2) | (f2bf(f3) << 16);
                }
            }
        }
    }
}

// ---------------- LayerNorm + LeakyReLU over bf16 rows of H=2048, in place ----------------
__device__ __forceinline__ float block_sum256(float v, float* red) {
#pragma unroll
    for (int o = 32; o > 0; o >>= 1) v += __shfl_down(v, o, 64);
    int w = threadIdx.x >> 6;
    if ((threadIdx.x & 63) == 0) red[w] = v;
    __syncthreads();
    float r = red[0] + red[1] + red[2] + red[3];
    __syncthreads();
    return r;
}

__global__ __launch_bounds__(256) void ln_leaky_kernel(
    unsigned short* __restrict__ Z, const float* __restrict__ gam,
    const float* __restrict__ bet) {
    __shared__ float red[4];
    unsigned short* zr = Z + (size_t)blockIdx.x * H_;
    const int tid = threadIdx.x;
    float v[8];
    float s = 0.f;
#pragma unroll
    for (int i = 0; i < 8; ++i) { v[i] = bf2f((unsigned)zr[tid + i * 256]); s += v[i]; }
    s = block_sum256(s, red);
    float mu = s * (1.f / H_);
    float qq = 0.f;
#pragma unroll
    for (int i = 0; i < 8; ++i) { float dd = v[i] - mu; qq += dd * dd; }
    qq = block_sum256(qq, red);
    float rs = rsqrtf(qq * (1.f / H_) + 1e-5f);
#pragma unroll
    for (int i = 0; i < 8; ++i) {
        int cc = tid + i * 256;
        float y = (v[i] - mu) * rs * gam[cc] + bet[cc];
        zr[cc] = (unsigned short)f2bf(y > 0.f ? y : 0.1f * y);
    }
}

// ---------------- theta-scan v5: r5 skeleton, lean hot loop ----------------
// 16 blocks x 1024 threads; block owns 2 batches. Two __syncthreads/step (r5-proven).
// sc split: 16 "reg" tiles rows 0-255 + 8 LDS tiles rows 256-383 + 8 L2-stream rows 384-511.
// Hot loop emits ONLY: sins (bf16, natural feat layout via 4x4 lane transpose, coalesced
// 8B stores) and msum=sum_d theta (f32, coalesced). g/feat/gb finished by post_kernel.
#define SCAN_LDS_BYTES 149760
// LDS: lds_sc [128][520]u16 @0 (133120 B) ; XT [16][520]u16 @133120 (16640 B)

__global__ __launch_bounds__(1024, 1) void scan_kernel(
    const unsigned short* __restrict__ scb,  // [512][512] bf16
    const float* __restrict__ gamma,         // [32][512][512] f32
    const float* __restrict__ omega,         // [512][4]
    unsigned short* __restrict__ featb,      // [32][512][2048] bf16: sin dump (pre-g)
    float* __restrict__ msum) {              // [32][512][512] f32: sum_d theta
    extern __shared__ char smem[];
    unsigned short* lds_sc = (unsigned short*)smem;
    unsigned short* XT = (unsigned short*)(smem + 133120);

    const int tid = threadIdx.x;
    const int w = tid >> 6, l = tid & 63;
    const int c = l & 15, q = l >> 4;
    const int h = c >> 3, bd = c & 7, bl = (c >> 2) & 1, d = c & 3;
    const int bglob = (int)blockIdx.x * 2 + bl;
    const int o0 = q * 4 + 2 * h;  // even row offset in tile; lane owns o0, o0+1

    // ---- stage LDS sc tiles (global rows 256..383) ----
    {
        const unsigned* g32 = (const unsigned*)scb;
        unsigned* l32 = (unsigned*)lds_sc;
        for (int it = 0; it < 32; ++it) {
            int idx = it * 1024 + tid;
            int row = idx >> 8, col = idx & 255;
            l32[row * 260 + col] = g32[(256 + row) * 256 + col];
        }
    }
    // ---- "register" tile: global rows [w*16, +16) ----
    short8_t areg[16];
    {
        const unsigned short* arow = scb + (size_t)(w * 16 + c) * 512 + q * 8;
#pragma unroll
        for (int kk = 0; kk < 16; ++kk)
            areg[kk] = *(const short8_t*)(arow + kk * 32);
    }
    // second tile source: LDS for waves 0-7 (rows 256..383), L2 stream for waves 8-15
    const unsigned short* al_base = lds_sc + (w * 16 + c) * 520 + q * 8;             // w<8
    const unsigned short* gs_base = scb + (size_t)(256 + w * 16 + c) * 512 + q * 8;  // w>=8
    const int i0 = w * 16 + o0;        // mi=0 global rows (+rr)
    const int i1 = 256 + w * 16 + o0;  // mi=1
    const int i_own = ((l & 2) ? i1 : i0) + (l & 1);  // row this lane dumps after transpose

    float om[2][2], th[2][2], sn[2][2], cs[2][2];
#pragma unroll
    for (int mi = 0; mi < 2; ++mi)
#pragma unroll
        for (int rr = 0; rr < 2; ++rr) {
            int i = (mi ? i1 : i0) + rr;
            om[mi][rr] = omega[i * 4 + d];
            th[mi][rr] = 0.f; sn[mi][rr] = 0.f; cs[mi][rr] = 1.f;
        }
    __syncthreads();

    for (int t = 0; t < T_; ++t) {
        // gamma loads (direct, r5-style)
        float gv[2][2];
        {
            const float* grow = gamma + ((size_t)bglob * 512 + t) * 512;
            gv[0][0] = grow[i0]; gv[0][1] = grow[i0 + 1];
            gv[1][0] = grow[i1]; gv[1][1] = grow[i1 + 1];
        }

        // MFMA coupling, split accumulators (2 chains of 8)
        float4_t a0a = {0.f, 0.f, 0.f, 0.f}, a0b = {0.f, 0.f, 0.f, 0.f};
        float4_t a1a = {0.f, 0.f, 0.f, 0.f}, a1b = {0.f, 0.f, 0.f, 0.f};
        if (t > 0) {
            const unsigned short* bt_base = XT + c * 520 + q * 8;
            if (w < 8) {
#pragma unroll
                for (int kk = 0; kk < 8; ++kk) {
                    short8_t bfA = *(const short8_t*)(bt_base + kk * 32);
                    short8_t bfB = *(const short8_t*)(bt_base + (kk + 8) * 32);
                    short8_t aA = *(const short8_t*)(al_base + kk * 32);
                    short8_t aB = *(const short8_t*)(al_base + (kk + 8) * 32);
                    a0a = __builtin_amdgcn_mfma_f32_16x16x32_bf16(areg[kk], bfA, a0a, 0, 0, 0);
                    a0b = __builtin_amdgcn_mfma_f32_16x16x32_bf16(areg[kk + 8], bfB, a0b, 0, 0, 0);
                    a1a = __builtin_amdgcn_mfma_f32_16x16x32_bf16(aA, bfA, a1a, 0, 0, 0);
                    a1b = __builtin_amdgcn_mfma_f32_16x16x32_bf16(aB, bfB, a1b, 0, 0, 0);
                }
            } else {
#pragma unroll
                for (int kk = 0; kk < 8; ++kk) {
                    short8_t bfA = *(const short8_t*)(bt_base + kk * 32);
                    short8_t bfB = *(const short8_t*)(bt_base + (kk + 8) * 32);
                    short8_t aA = *(const short8_t*)(gs_base + kk * 32);
                    short8_t aB = *(const short8_t*)(gs_base + (kk + 8) * 32);
                    a0a = __builtin_amdgcn_mfma_f32_16x16x32_bf16(areg[kk], bfA, a0a, 0, 0, 0);
                    a0b = __builtin_amdgcn_mfma_f32_16x16x32_bf16(areg[kk + 8], bfB, a0b, 0, 0, 0);
                    a1a = __builtin_amdgcn_mfma_f32_16x16x32_bf16(aA, bfA, a1a, 0, 0, 0);
                    a1b = __builtin_amdgcn_mfma_f32_16x16x32_bf16(aB, bfB, a1b, 0, 0, 0);
                }
            }
        }
        __syncthreads();  // sync1: all XT reads of step t complete

        // combine halves, theta update, hw sincos
#pragma unroll
        for (int mi = 0; mi < 2; ++mi) {
            float4_t acc;
            if (mi == 0) {
#pragma unroll
                for (int r = 0; r < 4; ++r) acc[r] = a0a[r] + a0b[r];
            } else {
#pragma unroll
                for (int r = 0; r < 4; ++r) acc[r] = a1a[r] + a1b[r];
            }
#pragma unroll
            for (int rr = 0; rr < 2; ++rr) {
                float own = h ? acc[2 + rr] : acc[rr];
                float send = h ? acc[rr] : acc[2 + rr];
                float recv = __shfl_xor(send, 8, 64);
                float Sst = h ? recv : own;
                float Sct = h ? own : recv;
                float coup = cs[mi][rr] * Sst - sn[mi][rr] * Sct;
                th[mi][rr] += 0.1f * (om[mi][rr] + gv[mi][rr] + (1.f / 512.f) * coup);
                sn[mi][rr] = sin_hw(th[mi][rr]);
                cs[mi][rr] = cos_hw(th[mi][rr]);
            }
        }

        // msum = sum over d (4-lane group reduce); lane stores its own (mi,rr)'s sum
        float ms00 = th[0][0], ms01 = th[0][1], ms10 = th[1][0], ms11 = th[1][1];
        ms00 += __shfl_xor(ms00, 1, 64); ms00 += __shfl_xor(ms00, 2, 64);
        ms01 += __shfl_xor(ms01, 1, 64); ms01 += __shfl_xor(ms01, 2, 64);
        ms10 += __shfl_xor(ms10, 1, 64); ms10 += __shfl_xor(ms10, 2, 64);
        ms11 += __shfl_xor(ms11, 1, 64); ms11 += __shfl_xor(ms11, 2, 64);
        float msj = (l & 2) ? ((l & 1) ? ms11 : ms10) : ((l & 1) ? ms01 : ms00);
        msum[((size_t)bglob * 512 + t) * 512 + i_own] = msj;

        // write new st/ct into XT (bf16 pairs) for step t+1
        unsigned sp0 = f2bf(sn[0][0]) | (f2bf(sn[0][1]) << 16);
        unsigned cp0 = f2bf(cs[0][0]) | (f2bf(cs[0][1]) << 16);
        unsigned sp1 = f2bf(sn[1][0]) | (f2bf(sn[1][1]) << 16);
        unsigned cp1 = f2bf(cs[1][0]) | (f2bf(cs[1][1]) << 16);
        ((unsigned*)XT)[(bd * 520 + i0) >> 1] = sp0;
        ((unsigned*)XT)[((8 + bd) * 520 + i0) >> 1] = cp0;
        ((unsigned*)XT)[(bd * 520 + i1) >> 1] = sp1;
        ((unsigned*)XT)[((8 + bd) * 520 + i1) >> 1] = cp1;

        // 4x4 lane transpose of sins -> natural feat layout, coalesced 8B store
        {
            float A0 = sn[0][0], A1 = sn[0][1], A2 = sn[1][0], A3 = sn[1][1];
            bool bit0 = (l & 1), bit1 = (l & 2);
            float sA = __shfl_xor(bit0 ? A0 : A1, 1, 64);
            float sB = __shfl_xor(bit0 ? A2 : A3, 1, 64);
            float B0 = bit0 ? sA : A0;
            float B1 = bit0 ? A1 : sA;
            float B2 = bit0 ? sB : A2;
            float B3 = bit0 ? A3 : sB;
            float sC = __shfl_xor(bit1 ? B0 : B2, 2, 64);
            float sD = __shfl_xor(bit1 ? B1 : B3, 2, 64);
            float c0 = bit1 ? sC : B0;
            float c1 = bit1 ? sD : B1;
            float c2 = bit1 ? B2 : sC;
            float c3 = bit1 ? B3 : sD;
            uint2 pk;
            pk.x = f2bf(c0) | (f2bf(c1) << 16);
            pk.y = f2bf(c2) | (f2bf(c3) << 16);
            *(uint2*)(featb + ((size_t)bglob * 512 + t) * 2048 + i_own * 4) = pk;
        }
        __syncthreads();  // sync2: XT writes visible for step t+1
    }
}

// ---------------- post: g from msum, featb *= g (in place), gb = bf16(g_t) ----------------
__global__ __launch_bounds__(256) void post_kernel(
    const float* __restrict__ msum,      // [32][512][512]
    unsigned short* __restrict__ featb,  // [32][512][2048] RMW
    unsigned short* __restrict__ gb) {   // [32][512][512]
    int idx = blockIdx.x * 256 + threadIdx.x;  // 8,388,608
    int i = idx & 511;
    int t = (idx >> 9) & 511;
    int b = idx >> 18;
    int t2 = t < 2 ? 0 : t - 2;
    float m2 = msum[((size_t)b * 512 + t2) * 512 + i];
    float g = 0.5f + 0.5f * sin_hw(m2 * 0.25f);
    uint2* fp = (uint2*)(featb + ((size_t)b * 512 + t) * 2048 + i * 4);
    uint2 v = *fp;
    float f0 = bf2f(v.x & 0xffffu) * g;
    float f1 = __uint_as_float(v.x & 0xffff0000u) * g;
    float f2 = bf2f(v.y & 0xffffu) * g;
    float f3 = __uint_as_float(v.y & 0xffff0000u) * g;
    v.x = f2bf(f0) | (f2bf(f1) << 16);
    v.y = f2bf(f2) | (f2bf(f3) << 16);
    *fp = v;
    float mt = msum[((size_t)b * 512 + t) * 512 + i];
    gb[((size_t)b * 512 + t) * 512 + i] =
        (unsigned short)f2bf(0.5f + 0.5f * sin_hw(mt * 0.25f));
}

// ---------------- LIF membrane scan: cur(f32) -> spike f32 (in place) + bf16 copy ----------------
__global__ __launch_bounds__(256) void mem_scan_kernel(
    float* __restrict__ io, unsigned short* __restrict__ spb) {
    int tid = blockIdx.x * 256 + threadIdx.x;  // 65536 = B*H
    int h = tid & (H_ - 1), b = tid >> 11;
    float mem = 0.f;
    float* base = io + (size_t)b * T_ * H_ + h;
    unsigned short* sb = spb + (size_t)b * T_ * H_ + h;
    for (int t = 0; t < T_; ++t) {
        float cur = base[(size_t)t * H_];
        mem = 0.5f * mem + cur;
        float sp = 1.f / (1.f + __expf(-4.f * (mem - 1.f)));
        mem -= sp;
        base[(size_t)t * H_] = sp;
        sb[(size_t)t * H_] = (unsigned short)f2bf(sp);
    }
}

// ---------------- conv1d(k=5,pad=2) over T + log_softmax over C ----------------
__global__ __launch_bounds__(128) void conv_lsm_kernel(
    const float* __restrict__ snn, const float* __restrict__ Wc,
    const float* __restrict__ bc, float* __restrict__ out0) {
    __shared__ float sl[36 * 128];
    const int b = blockIdx.x >> 4;
    const int tt0 = (blockIdx.x & 15) * 32;
    const int co = threadIdx.x;
    for (int r = 0; r < 36; ++r) {
        int t = tt0 + r - 2;
        sl[r * 128 + co] = (t >= 0 && t < T_) ? snn[(size_t)(b * T_ + t) * 128 + co] : 0.f;
    }
    __syncthreads();
    float acc[32];
#pragma unroll
    for (int i = 0; i < 32; ++i) acc[i] = 0.f;
    for (int ci = 0; ci < 128; ++ci) {
        const float* wp = &Wc[(size_t)(co * 128 + ci) * 5];
        float w0 = wp[0], w1 = wp[1], w2 = wp[2], w3 = wp[3], w4 = wp[4];
        const float* col = &sl[ci];
        float r0 = col[0 * 128], r1 = col[1 * 128], r2 = col[2 * 128], r3 = col[3 * 128];
#pragma unroll
        for (int i = 0; i < 32; ++i) {
            float r4 = col[(i + 4) * 128];
            acc[i] += w0 * r0 + w1 * r1 + w2 * r2 + w3 * r3 + w4 * r4;
            r0 = r1; r1 = r2; r2 = r3; r3 = r4;
        }
    }
    float bco = bc[co];
    __syncthreads();
    float* cl = sl;
#pragma unroll
    for (int i = 0; i < 32; ++i) cl[i * 129 + co] = acc[i] + bco;
    __syncthreads();
    if (co < 32) {
        int t = tt0 + co;
        float mx = -3.4e38f;
        for (int cc = 0; cc < 128; ++cc) mx = fmaxf(mx, cl[co * 129 + cc]);
        float se = 0.f;
        for (int cc = 0; cc < 128; ++cc) se += __expf(cl[co * 129 + cc] - mx);
        float lse = mx + __logf(se);
        for (int cc = 0; cc < 128; ++cc)
            out0[((size_t)(b * 128 + cc)) * T_ + t] = cl[co * 129 + cc] - lse;
    }
}

// ---------------- launch ----------------
extern "C" void kernel_launch(void* const* d_in, const int* in_sizes, int n_in,
                              void* d_out, int out_size, void* d_ws, size_t ws_size,
                              hipStream_t stream) {
    (void)in_sizes; (void)n_in; (void)out_size; (void)ws_size;
    const float* x      = (const float*)d_in[0];
    const float* sc     = (const float*)d_in[1];
    const float* W_proj = (const float*)d_in[2];
    const float* b_proj = (const float*)d_in[3];
    const float* ln_g   = (const float*)d_in[4];
    const float* ln_b   = (const float*)d_in[5];
    const float* W_enc  = (const float*)d_in[6];
    const float* b_enc  = (const float*)d_in[7];
    const float* omega  = (const float*)d_in[8];
    const float* W_mask = (const float*)d_in[9];
    const float* b_mask = (const float*)d_in[10];
    const float* W_in   = (const float*)d_in[11];
    const float* b_in   = (const float*)d_in[12];
    const float* W_out  = (const float*)d_in[13];
    const float* b_out  = (const float*)d_in[14];
    const float* W_conv = (const float*)d_in[15];
    const float* b_conv = (const float*)d_in[16];

    float* out0 = (float*)d_out;                   // [B,C,T]
    float* out1 = out0 + (size_t)B_ * C_ * T_;     // [B,T,H] f32: cur -> spikes

    const int M = B_ * T_;  // 16384
    char* w = (char*)d_ws;
    float*          gamma  = (float*)w;                         // @0          33,554,432
    unsigned short* featb  = (unsigned short*)(w + 33554432);   // @33.5M      67,108,864
    float*          msum   = (float*)(w + 100663296);           // @100.7M     33,554,432
    unsigned short* gb     = (unsigned short*)(w + 134217728);  // @134.2M     16,777,216
    unsigned short* scb    = (unsigned short*)(w + 150994944);  // @151.0M        524,288
    unsigned short* wprojT = (unsigned short*)(w + 151519232);  // [2048,512]   2,097,152
    unsigned short* wencT  = (unsigned short*)(w + 153616384);  // [512,2048]   2,097,152
    unsigned short* winT   = (unsigned short*)(w + 155713536);  // [2048,2048]  8,388,608
    unsigned short* woutT  = (unsigned short*)(w + 164102144);  // [128,2048]     524,288
    unsigned short* wmT    = (unsigned short*)(w + 164626432);  // [512,512]      524,288
    unsigned short* xb  = gb;      // alias: xb dead before post writes gb
    unsigned short* Zb  = featb;   // alias: Z dead before scan writes featb
    unsigned short* spb = featb;   // alias: featb dead after G3
    float* snn_pre = gamma;        // alias: gamma dead after scan

    // conversions
    cvt_bf16_kernel<<<512, 256, 0, stream>>>(sc, (unsigned*)scb, 131072);
    cvt_bf16_kernel<<<16384, 256, 0, stream>>>(x, (unsigned*)xb, 4194304);
    cvt_T_kernel<<<dim3(64, 16), 256, 0, stream>>>(W_proj, wprojT, 512, 2048);
    cvt_T_kernel<<<dim3(16, 64), 256, 0, stream>>>(W_enc, wencT, 2048, 512);
    cvt_T_kernel<<<dim3(64, 64), 256, 0, stream>>>(W_in, winT, 2048, 2048);
    cvt_T_kernel<<<dim3(4, 64), 256, 0, stream>>>(W_out, woutT, 2048, 128);
    cvt_T_kernel<<<dim3(16, 16), 256, 0, stream>>>(W_mask, wmT, 512, 512);

    // G1: Zb = bf16(x @ W_proj + b_proj)
    gemm_bf16<1, false><<<dim3(16, 128), 256, 0, stream>>>(xb, wprojT, b_proj, Zb, M, H_, N_);
    // LN + LeakyReLU in place (bf16)
    ln_leaky_kernel<<<M, 256, 0, stream>>>(Zb, ln_g, ln_b);
    // G2: gamma(f32) = Zb @ W_enc + b_enc
    gemm_bf16<0, false><<<dim3(4, 128), 256, 0, stream>>>(Zb, wencT, b_enc, gamma, M, N_, H_);
    // theta scan -> featb (sin dump), msum
    scan_kernel<<<16, 1024, SCAN_LDS_BYTES, stream>>>(scb, gamma, omega, featb, msum);
    // post: featb *= g_{t-2}, gb = bf16(g(theta_t))
    post_kernel<<<32768, 256, 0, stream>>>(msum, featb, gb);
    // deferred mask: featb *= sigmoid(gb_shift @ W_mask + b_mask)
    gemm_bf16<2, true><<<dim3(4, 128), 256, 0, stream>>>(gb, wmT, b_mask, featb, M, N_, N_);
    // G3: cur(f32, out1) = featb @ W_in + b_in
    gemm_bf16<0, false><<<dim3(16, 128), 256, 0, stream>>>(featb, winT, b_in, out1, M, H_, N_ * D_);
    // LIF membrane scan in place + bf16 spikes
    mem_scan_kernel<<<256, 256, 0, stream>>>(out1, spb);
    // G4: snn_pre(f32) = spikes @ W_out + b_out
    gemm_bf16<0, false><<<dim3(1, 128), 256, 0, stream>>>(spb, woutT, b_out, snn_pre, M, C_, H_);
    // conv1d + log_softmax -> out0
    conv_lsm_kernel<<<dim3(B_ * 16), 128, 0, stream>>>(snn_pre, W_conv, b_conv, out0);
}